// Round 3
// baseline (405.442 us; speedup 1.0000x reference)
//
#include <hip/hip_runtime.h>
#include <cstdint>
#include <cstddef>

// Problem constants
#define Bsz   32
#define Ssz   2048
#define Tsz   768
#define NH    8
#define DH    96
#define DHID  384
#define Ncols (NH*DH)       // 768

using u16 = unsigned short;
typedef __bf16 bf16x8 __attribute__((ext_vector_type(8)));
typedef __bf16 bf16x4 __attribute__((ext_vector_type(4)));
typedef float  f32x4  __attribute__((ext_vector_type(4)));

// native bf16 convert (compiler emits v_cvt_pk_bf16_f32 for pairs; RNE)
__device__ __forceinline__ u16 f2bn(float f) {
  __bf16 h = (__bf16)f;
  return __builtin_bit_cast(u16, h);
}
__device__ __forceinline__ float b2f(u16 u) {
  return __builtin_bit_cast(float, (uint32_t)u << 16);
}

// ---------------------------------------------------------------------------
// Kernel 1: pack weights to bf16, transposed so MFMA frags are contiguous in K
//   B1t[n][k]  (n = h*96+d, k in [0,768))  <- P_w[h][k][d]
//   W1t[h][n][k] (n<384, k<96)             <- W1_w[h][k][n]
//   W2t[h][n][k] (n<96,  k<384)            <- W2_w[h][k][n]
// ---------------------------------------------------------------------------
__global__ __launch_bounds__(256) void k_pack(const float* __restrict__ Pw,
    const float* __restrict__ W1w, const float* __restrict__ W2w,
    u16* __restrict__ B1t, u16* __restrict__ W1t, u16* __restrict__ W2t)
{
  int i = blockIdx.x * 256 + threadIdx.x;
  if (i < 589824) {
    int n = i / 768, k = i % 768;
    int h = n / 96, d = n % 96;
    B1t[i] = f2bn(Pw[(size_t)h*73728 + (size_t)k*96 + d]);
  } else if (i < 589824 + 294912) {
    int j = i - 589824;
    int h = j / 36864, r = j % 36864;
    int n = r / 96, k = r % 96;
    W1t[j] = f2bn(W1w[(size_t)h*36864 + (size_t)k*384 + n]);
  } else if (i < 589824 + 2*294912) {
    int q = i - 589824 - 294912;
    int h = q / 36864, r = q % 36864;
    int n = r / 384, k = r % 384;
    W2t[q] = f2bn(W2w[(size_t)h*36864 + (size_t)k*96 + n]);
  }
}

// ---------------------------------------------------------------------------
// Kernel 2: Hi[65536][768] (bf16) = emb(fp32->bf16) @ B1 + P_b
// 128x128 tile, BK=32, 4 waves (2x2), mfma_f32_16x16x32_bf16.
// Bijective XCD-chunked swizzle for emb L2 reuse.
// ---------------------------------------------------------------------------
__global__ __launch_bounds__(256) void k_gemm1(const float* __restrict__ emb,
    const u16* __restrict__ B1t, const float* __restrict__ Pb, u16* __restrict__ Hi)
{
  __shared__ u16 As[128][40];   // +8 pad: conflict-free b128 reads
  __shared__ u16 Bs[128][40];
  const int tid  = threadIdx.x;
  const int lane = tid & 63;
  const int wid  = tid >> 6;
  const int wr = wid >> 1, wc = wid & 1;
  const int L = blockIdx.x;                 // 0..3071
  const int widx = (L & 7) * 384 + (L >> 3);
  const int bm = widx / 6, bn = widx % 6;
  const int l15 = lane & 15, lg = lane >> 4;

  f32x4 acc[4][4] = {};
  for (int kt = 0; kt < Tsz/32; ++kt) {
    const int k0 = kt * 32;
    #pragma unroll
    for (int i = 0; i < 4; ++i) {
      int g = tid + i*256;
      int row = g >> 3, seg = g & 7;
      float4 v = *reinterpret_cast<const float4*>(
          emb + (size_t)(bm*128 + row)*Tsz + k0 + seg*4);
      bf16x4 t;
      t[0] = (__bf16)v.x; t[1] = (__bf16)v.y; t[2] = (__bf16)v.z; t[3] = (__bf16)v.w;
      *reinterpret_cast<uint2*>(&As[row][seg*4]) = __builtin_bit_cast(uint2, t);
    }
    #pragma unroll
    for (int i = 0; i < 2; ++i) {
      int g = tid + i*256;
      int row = g >> 2, seg = g & 3;
      uint4 v = *reinterpret_cast<const uint4*>(
          B1t + (size_t)(bn*128 + row)*Tsz + k0 + seg*8);
      *reinterpret_cast<uint4*>(&Bs[row][seg*8]) = v;
    }
    __syncthreads();
    bf16x8 a[4], b[4];
    #pragma unroll
    for (int r = 0; r < 4; ++r)
      a[r] = *reinterpret_cast<const bf16x8*>(&As[wr*64 + r*16 + l15][lg*8]);
    #pragma unroll
    for (int c = 0; c < 4; ++c)
      b[c] = *reinterpret_cast<const bf16x8*>(&Bs[wc*64 + c*16 + l15][lg*8]);
    #pragma unroll
    for (int r = 0; r < 4; ++r)
      #pragma unroll
      for (int c = 0; c < 4; ++c)
        acc[r][c] = __builtin_amdgcn_mfma_f32_16x16x32_bf16(a[r], b[c], acc[r][c], 0, 0, 0);
    __syncthreads();
  }
  #pragma unroll
  for (int c = 0; c < 4; ++c) {
    int col = bn*128 + wc*64 + c*16 + l15;
    float bias = Pb[col];
    #pragma unroll
    for (int r = 0; r < 4; ++r) {
      int row0 = bm*128 + wr*64 + r*16 + lg*4;
      #pragma unroll
      for (int j = 0; j < 4; ++j)
        Hi[(size_t)(row0 + j)*Ncols + col] = f2bn(acc[r][c][j] + bias);
    }
  }
}

// ---------------------------------------------------------------------------
// Kernel 3 (v3): fused FFN + online-softmax partials, minimal LDS.
// Grid (chunk=32, h=8, b=32); block 128 = 2 independent waves; 64 rows/block,
// 32 rows (2 strips of 16) per wave. No HiS: phase-1 Hi lives in registers
// (hifr), tail Hi values re-read from L1/L2. One barrier (final merge only).
//
// Phase 1 (swapped): D = mfma(A=W1^T-frag, B=Hi-frag) -> lane holds
//   Z[row=l15][n = c*32 + t*16 + lg*4 + reg]  -> b64 LDS bounce (Zb)
// Read back b128: Z[row=l15][k = c*32 + lg*8 + j] = phase-2 A-frag.
// Phase 2: D = mfma(A=Z-frag, B=W2-frag) -> lane holds
//   L[row = lg*4+reg][d = ct*16 + l15]  -> in-register column softmax.
// ---------------------------------------------------------------------------
__global__ __launch_bounds__(128, 3) void k_ffn_pool(
    const u16* __restrict__ Hi, const u16* __restrict__ W1t, const u16* __restrict__ W2t,
    const float* __restrict__ b1, const float* __restrict__ b2v, const float* __restrict__ mask,
    float* __restrict__ Pm, float* __restrict__ Pl, float* __restrict__ Pa)
{
  __shared__ u16 Zb[2][2][16][40];                 // 5120 B (per wave, per strip)
  __shared__ float mb[2][96], lb[2][96], ab[2][96];// 2304 B

  const int tid = threadIdx.x, lane = tid & 63, w = tid >> 6;
  const int l15 = lane & 15, lg = lane >> 4;
  const int chunk = blockIdx.x, h = blockIdx.y, b = blockIdx.z;
  const size_t rbase = (size_t)b * Ssz + (size_t)chunk * 64 + (size_t)w * 32;

  // mask logs for this lane's 8 tail rows
  float lmv[2][4];
  #pragma unroll
  for (int ls = 0; ls < 2; ++ls) {
    float4 mk = *reinterpret_cast<const float4*>(&mask[rbase + ls*16 + lg*4]);
    lmv[ls][0] = __logf(mk.x); lmv[ls][1] = __logf(mk.y);
    lmv[ls][2] = __logf(mk.z); lmv[ls][3] = __logf(mk.w);
  }

  // Hi fragments: wave's 32 rows x 96 cols entirely in registers
  bf16x8 hifr[2][3];
  #pragma unroll
  for (int ls = 0; ls < 2; ++ls)
    #pragma unroll
    for (int ks = 0; ks < 3; ++ks)
      hifr[ls][ks] = *reinterpret_cast<const bf16x8*>(
          Hi + (rbase + ls*16 + l15)*Ncols + h*DH + ks*32 + lg*8);

  const u16* W1h = W1t + (size_t)h * DHID * DH;
  const u16* W2h = W2t + (size_t)h * DH * DHID;
  const float* b1h = b1 + h * DHID;

  f32x4 lgt[2][6] = {};

  #pragma unroll 1
  for (int c = 0; c < 12; ++c) {      // 12 chunks of 32 n-values
    const u16* W1c = W1h + c*32*DH;
    const u16* W2c = W2h + c*32;
    bf16x8 a1[2][3];
    #pragma unroll
    for (int t = 0; t < 2; ++t)
      #pragma unroll
      for (int ks = 0; ks < 3; ++ks)
        a1[t][ks] = *reinterpret_cast<const bf16x8*>(
            W1c + (size_t)(t*16 + l15)*DH + ks*32 + lg*8);
    bf16x8 b2fr[6];
    #pragma unroll
    for (int ct = 0; ct < 6; ++ct)
      b2fr[ct] = *reinterpret_cast<const bf16x8*>(
          W2c + (size_t)(ct*16 + l15)*DHID + lg*8);
    float4 bia0 = *reinterpret_cast<const float4*>(b1h + c*32 + lg*4);
    float4 bia1 = *reinterpret_cast<const float4*>(b1h + c*32 + 16 + lg*4);

    #pragma unroll
    for (int ls = 0; ls < 2; ++ls) {
      f32x4 z0 = {}, z1 = {};
      #pragma unroll
      for (int ks = 0; ks < 3; ++ks) {
        z0 = __builtin_amdgcn_mfma_f32_16x16x32_bf16(a1[0][ks], hifr[ls][ks], z0, 0, 0, 0);
        z1 = __builtin_amdgcn_mfma_f32_16x16x32_bf16(a1[1][ks], hifr[ls][ks], z1, 0, 0, 0);
      }
      bf16x4 p0, p1;
      p0[0] = (__bf16)fmaxf(z0[0] + bia0.x, 0.f);
      p0[1] = (__bf16)fmaxf(z0[1] + bia0.y, 0.f);
      p0[2] = (__bf16)fmaxf(z0[2] + bia0.z, 0.f);
      p0[3] = (__bf16)fmaxf(z0[3] + bia0.w, 0.f);
      p1[0] = (__bf16)fmaxf(z1[0] + bia1.x, 0.f);
      p1[1] = (__bf16)fmaxf(z1[1] + bia1.y, 0.f);
      p1[2] = (__bf16)fmaxf(z1[2] + bia1.z, 0.f);
      p1[3] = (__bf16)fmaxf(z1[3] + bia1.w, 0.f);
      *reinterpret_cast<uint2*>(&Zb[w][ls][l15][lg*4])      = __builtin_bit_cast(uint2, p0);
      *reinterpret_cast<uint2*>(&Zb[w][ls][l15][16 + lg*4]) = __builtin_bit_cast(uint2, p1);
      bf16x8 zfrag = *reinterpret_cast<const bf16x8*>(&Zb[w][ls][l15][lg*8]);
      #pragma unroll
      for (int ct = 0; ct < 6; ++ct)
        lgt[ls][ct] = __builtin_amdgcn_mfma_f32_16x16x32_bf16(zfrag, b2fr[ct], lgt[ls][ct], 0, 0, 0);
    }
  }

  // ---- tail: per-column softmax partials over this wave's 32 rows ----
  float b2s[6];
  #pragma unroll
  for (int ct = 0; ct < 6; ++ct) b2s[ct] = b2v[h*DH + ct*16 + l15];

  // row-major Hi values for the weighted sum (L1/L2-hot: just read above)
  float G[2][6][4];
  #pragma unroll
  for (int ls = 0; ls < 2; ++ls)
    #pragma unroll
    for (int ct = 0; ct < 6; ++ct)
      #pragma unroll
      for (int j = 0; j < 4; ++j)
        G[ls][ct][j] = b2f(Hi[(rbase + ls*16 + lg*4 + j)*Ncols + h*DH + ct*16 + l15]);

  float fm[6], fl[6], fa[6];
  #pragma unroll
  for (int ct = 0; ct < 6; ++ct) {
    float mm[2], ll[2], aa[2];
    #pragma unroll
    for (int ls = 0; ls < 2; ++ls) {
      float av0 = lgt[ls][ct][0] + b2s[ct] + lmv[ls][0];
      float av1 = lgt[ls][ct][1] + b2s[ct] + lmv[ls][1];
      float av2 = lgt[ls][ct][2] + b2s[ct] + lmv[ls][2];
      float av3 = lgt[ls][ct][3] + b2s[ct] + lmv[ls][3];
      float m = fmaxf(fmaxf(av0, av1), fmaxf(av2, av3));
      m = fmaxf(m, __shfl_xor(m, 16));
      m = fmaxf(m, __shfl_xor(m, 32));
      float p0 = __expf(av0 - m), p1 = __expf(av1 - m);
      float p2 = __expf(av2 - m), p3 = __expf(av3 - m);
      float l = (p0 + p1) + (p2 + p3);
      float a = (p0*G[ls][ct][0] + p1*G[ls][ct][1]) + (p2*G[ls][ct][2] + p3*G[ls][ct][3]);
      l += __shfl_xor(l, 16); l += __shfl_xor(l, 32);
      a += __shfl_xor(a, 16); a += __shfl_xor(a, 32);
      mm[ls] = m; ll[ls] = l; aa[ls] = a;
    }
    float M  = fmaxf(mm[0], mm[1]);
    float e0 = __expf(mm[0] - M), e1 = __expf(mm[1] - M);
    fm[ct] = M;
    fl[ct] = ll[0]*e0 + ll[1]*e1;
    fa[ct] = aa[0]*e0 + aa[1]*e1;
  }
  if (lane < 16) {
    #pragma unroll
    for (int ct = 0; ct < 6; ++ct) {
      mb[w][ct*16 + l15] = fm[ct];
      lb[w][ct*16 + l15] = fl[ct];
      ab[w][ct*16 + l15] = fa[ct];
    }
  }
  __syncthreads();
  if (tid < 96) {
    float m = fmaxf(mb[0][tid], mb[1][tid]);
    float e0 = __expf(mb[0][tid] - m), e1 = __expf(mb[1][tid] - m);
    float l = lb[0][tid]*e0 + lb[1][tid]*e1;
    float a = ab[0][tid]*e0 + ab[1][tid]*e1;
    size_t pidx = (((size_t)(b*NH + h)*32 + chunk)*96) + tid;
    Pm[pidx] = m; Pl[pidx] = l; Pa[pidx] = a;
  }
}

// ---------------------------------------------------------------------------
// Kernel 4: merge 32 chunk partials per (b,h,d) -> out[b][h*96+d]
// ---------------------------------------------------------------------------
__global__ __launch_bounds__(256) void k_merge(const float* __restrict__ Pm,
    const float* __restrict__ Pl, const float* __restrict__ Pa, float* __restrict__ out)
{
  int idx = blockIdx.x * 256 + threadIdx.x;
  if (idx >= Bsz*NH*DH) return;
  int d = idx % 96;
  int bh = idx / 96;
  const float* pm = Pm + (size_t)bh*32*96 + d;
  const float* pl = Pl + (size_t)bh*32*96 + d;
  const float* pa = Pa + (size_t)bh*32*96 + d;
  float m = -3.4e38f;
  #pragma unroll
  for (int c = 0; c < 32; ++c) m = fmaxf(m, pm[c*96]);
  float l = 0.f, a = 0.f;
  #pragma unroll
  for (int c = 0; c < 32; ++c) {
    float sc = __expf(pm[c*96] - m);
    l += pl[c*96] * sc;
    a += pa[c*96] * sc;
  }
  out[idx] = a / l;
}

// ---------------------------------------------------------------------------
// Workspace layout (bytes), total ~112.5 MB (round-1 proven size):
//   Hi  bf16 : 0           (100663296)
//   B1t bf16 : 100663296   (1179648)
//   W1t bf16 : 101842944   (589824)
//   W2t bf16 : 102432768   (589824)
//   Pm  f32  : 103022592   (3145728)
//   Pl  f32  : 106168320   (3145728)
//   Pa  f32  : 109314048   (3145728)
// ---------------------------------------------------------------------------
extern "C" void kernel_launch(void* const* d_in, const int* in_sizes, int n_in,
                              void* d_out, int out_size, void* d_ws, size_t ws_size,
                              hipStream_t stream)
{
  const float* emb  = (const float*)d_in[0];
  const float* mask = (const float*)d_in[1];
  const float* Pw   = (const float*)d_in[2];
  const float* Pb   = (const float*)d_in[3];
  const float* W1w  = (const float*)d_in[4];
  const float* W1b  = (const float*)d_in[5];
  const float* W2w  = (const float*)d_in[6];
  const float* W2b  = (const float*)d_in[7];
  float* out = (float*)d_out;

  char* ws = (char*)d_ws;
  u16*   Hi  = (u16*)(ws);
  u16*   B1t = (u16*)(ws + 100663296ull);
  u16*   W1t = (u16*)(ws + 101842944ull);
  u16*   W2t = (u16*)(ws + 102432768ull);
  float* Pm  = (float*)(ws + 103022592ull);
  float* Pl  = (float*)(ws + 106168320ull);
  float* Pa  = (float*)(ws + 109314048ull);

  k_pack<<<dim3(4608), dim3(256), 0, stream>>>(Pw, W1w, W2w, B1t, W1t, W2t);
  k_gemm1<<<dim3(3072), dim3(256), 0, stream>>>(emb, B1t, Pb, Hi);
  k_ffn_pool<<<dim3(32, 8, 32), dim3(128), 0, stream>>>(Hi, W1t, W2t, W1b, W2b, mask, Pm, Pl, Pa);
  k_merge<<<dim3(96), dim3(256), 0, stream>>>(Pm, Pl, Pa, out);
}

// Round 4
// 304.132 us; speedup vs baseline: 1.3331x; 1.3331x over previous
//
#include <hip/hip_runtime.h>
#include <cstdint>
#include <cstddef>

// Problem constants
#define Bsz   32
#define Ssz   2048
#define Tsz   768
#define NH    8
#define DH    96
#define DHID  384
#define Ncols (NH*DH)       // 768

using u16 = unsigned short;
typedef __bf16 bf16x8 __attribute__((ext_vector_type(8)));
typedef __bf16 bf16x4 __attribute__((ext_vector_type(4)));
typedef float  f32x4  __attribute__((ext_vector_type(4)));

__device__ __forceinline__ u16 f2bn(float f) {
  __bf16 h = (__bf16)f;
  return __builtin_bit_cast(u16, h);
}
__device__ __forceinline__ float b2f(u16 u) {
  return __builtin_bit_cast(float, (uint32_t)u << 16);
}

// ---------------------------------------------------------------------------
// Kernel 1: pack weights to bf16, transposed so MFMA frags are contiguous in K
//   B1t[n][k]  (n = h*96+d, k in [0,768))  <- P_w[h][k][d]
//   W1t[h][n][k] (n<384, k<96)             <- W1_w[h][k][n]
//   W2t[h][n][k] (n<96,  k<384)            <- W2_w[h][k][n]
// ---------------------------------------------------------------------------
__global__ __launch_bounds__(256) void k_pack(const float* __restrict__ Pw,
    const float* __restrict__ W1w, const float* __restrict__ W2w,
    u16* __restrict__ B1t, u16* __restrict__ W1t, u16* __restrict__ W2t)
{
  int i = blockIdx.x * 256 + threadIdx.x;
  if (i < 589824) {
    int n = i / 768, k = i % 768;
    int h = n / 96, d = n % 96;
    B1t[i] = f2bn(Pw[(size_t)h*73728 + (size_t)k*96 + d]);
  } else if (i < 589824 + 294912) {
    int j = i - 589824;
    int h = j / 36864, r = j % 36864;
    int n = r / 96, k = r % 96;
    W1t[j] = f2bn(W1w[(size_t)h*36864 + (size_t)k*384 + n]);
  } else if (i < 589824 + 2*294912) {
    int q = i - 589824 - 294912;
    int h = q / 36864, r = q % 36864;
    int n = r / 384, k = r % 384;
    W2t[q] = f2bn(W2w[(size_t)h*36864 + (size_t)k*96 + n]);
  }
}

// ---------------------------------------------------------------------------
// Kernel 2: Hi[65536][768] (bf16) = emb(fp32->bf16) @ B1 + P_b  (unchanged)
// ---------------------------------------------------------------------------
__global__ __launch_bounds__(256) void k_gemm1(const float* __restrict__ emb,
    const u16* __restrict__ B1t, const float* __restrict__ Pb, u16* __restrict__ Hi)
{
  __shared__ u16 As[128][40];
  __shared__ u16 Bs[128][40];
  const int tid  = threadIdx.x;
  const int lane = tid & 63;
  const int wid  = tid >> 6;
  const int wr = wid >> 1, wc = wid & 1;
  const int L = blockIdx.x;                 // 0..3071
  const int widx = (L & 7) * 384 + (L >> 3);
  const int bm = widx / 6, bn = widx % 6;
  const int l15 = lane & 15, lg = lane >> 4;

  f32x4 acc[4][4] = {};
  for (int kt = 0; kt < Tsz/32; ++kt) {
    const int k0 = kt * 32;
    #pragma unroll
    for (int i = 0; i < 4; ++i) {
      int g = tid + i*256;
      int row = g >> 3, seg = g & 7;
      float4 v = *reinterpret_cast<const float4*>(
          emb + (size_t)(bm*128 + row)*Tsz + k0 + seg*4);
      bf16x4 t;
      t[0] = (__bf16)v.x; t[1] = (__bf16)v.y; t[2] = (__bf16)v.z; t[3] = (__bf16)v.w;
      *reinterpret_cast<uint2*>(&As[row][seg*4]) = __builtin_bit_cast(uint2, t);
    }
    #pragma unroll
    for (int i = 0; i < 2; ++i) {
      int g = tid + i*256;
      int row = g >> 2, seg = g & 3;
      uint4 v = *reinterpret_cast<const uint4*>(
          B1t + (size_t)(bn*128 + row)*Tsz + k0 + seg*8);
      *reinterpret_cast<uint4*>(&Bs[row][seg*8]) = v;
    }
    __syncthreads();
    bf16x8 a[4], b[4];
    #pragma unroll
    for (int r = 0; r < 4; ++r)
      a[r] = *reinterpret_cast<const bf16x8*>(&As[wr*64 + r*16 + l15][lg*8]);
    #pragma unroll
    for (int c = 0; c < 4; ++c)
      b[c] = *reinterpret_cast<const bf16x8*>(&Bs[wc*64 + c*16 + l15][lg*8]);
    #pragma unroll
    for (int r = 0; r < 4; ++r)
      #pragma unroll
      for (int c = 0; c < 4; ++c)
        acc[r][c] = __builtin_amdgcn_mfma_f32_16x16x32_bf16(a[r], b[c], acc[r][c], 0, 0, 0);
    __syncthreads();
  }
  #pragma unroll
  for (int c = 0; c < 4; ++c) {
    int col = bn*128 + wc*64 + c*16 + l15;
    float bias = Pb[col];
    #pragma unroll
    for (int r = 0; r < 4; ++r) {
      int row0 = bm*128 + wr*64 + r*16 + lg*4;
      #pragma unroll
      for (int j = 0; j < 4; ++j)
        Hi[(size_t)(row0 + j)*Ncols + col] = f2bn(acc[r][c][j] + bias);
    }
  }
}

// ---------------------------------------------------------------------------
// Kernel 3 (v4): persistent per-(h,b) block, fully fused FFN + softmax pool.
// Grid (h=8, b=32) = 256 blocks (1/CU); block = 4 waves; wave owns 512 rows
// processed as 8 passes x 64 rows (4 strips of 16). W2_h staged in LDS once;
// W1 frags from L1/L2 (4 waves reuse); Z bounced through per-wave LDS slots;
// online-softmax (M,L,A) carried in registers across passes; block writes
// out[b][h*96+d] directly. No main-loop barriers, no partial buffers.
// ---------------------------------------------------------------------------
__global__ __launch_bounds__(256, 1) void k_ffn_pool(
    const u16* __restrict__ Hi, const u16* __restrict__ W1t, const u16* __restrict__ W2t,
    const float* __restrict__ b1, const float* __restrict__ b2v, const float* __restrict__ mask,
    float* __restrict__ out)
{
  __shared__ u16 W2s[96][392];              // 74.5 KB, stride 784B (16B-mult, uniform banks)
  __shared__ u16 Zb[4][2][16][40];          // 10 KB: per-wave, 2 bounce slots
  __shared__ float mb[4][96], lb[4][96], ab[4][96];  // 4.5 KB merge

  const int tid = threadIdx.x, lane = tid & 63, w = tid >> 6;
  const int l15 = lane & 15, lg = lane >> 4;
  const int h = blockIdx.x, b = blockIdx.y;

  const u16* W1h = W1t + (size_t)h * DHID * DH;
  const u16* W2h = W2t + (size_t)h * DH * DHID;
  const float* b1h = b1 + h * DHID;

  // stage W2_h -> LDS (96 rows x 384 bf16)
  for (int i = tid; i < 96*48; i += 256) {
    int r = i / 48, g = i % 48;
    uint4 v = *reinterpret_cast<const uint4*>(W2h + (size_t)r*DHID + g*8);
    *reinterpret_cast<uint4*>(&W2s[r][g*8]) = v;
  }
  __syncthreads();

  float b2s[6];
  #pragma unroll
  for (int ct = 0; ct < 6; ++ct) b2s[ct] = b2v[h*DH + ct*16 + l15];

  float Mr[6], Lr[6], Ar[6];
  #pragma unroll
  for (int ct = 0; ct < 6; ++ct) { Mr[ct] = -3.4e38f; Lr[ct] = 0.f; Ar[ct] = 0.f; }

  #pragma unroll 1
  for (int pass = 0; pass < 8; ++pass) {
    const size_t prow = (size_t)b*Ssz + (size_t)w*512 + (size_t)pass*64;

    // Hi fragments: 4 strips x 16 rows x 96 cols in registers
    bf16x8 hifr[4][3];
    #pragma unroll
    for (int s = 0; s < 4; ++s)
      #pragma unroll
      for (int ks = 0; ks < 3; ++ks)
        hifr[s][ks] = *reinterpret_cast<const bf16x8*>(
            Hi + (prow + s*16 + l15)*Ncols + h*DH + ks*32 + lg*8);

    f32x4 lgt[4][6] = {};

    #pragma unroll 2
    for (int c = 0; c < 12; ++c) {
      // W1 A-frags from global (L1/L2-shared across the 4 waves)
      bf16x8 a1c[2][3];
      #pragma unroll
      for (int t = 0; t < 2; ++t)
        #pragma unroll
        for (int ks = 0; ks < 3; ++ks)
          a1c[t][ks] = *reinterpret_cast<const bf16x8*>(
              W1h + (size_t)(c*32 + t*16 + l15)*DH + ks*32 + lg*8);
      float4 bc0 = *reinterpret_cast<const float4*>(b1h + c*32 + lg*4);
      float4 bc1 = *reinterpret_cast<const float4*>(b1h + c*32 + 16 + lg*4);
      // W2 B-frags from LDS
      bf16x8 b2fr[6];
      #pragma unroll
      for (int ct = 0; ct < 6; ++ct)
        b2fr[ct] = *reinterpret_cast<const bf16x8*>(&W2s[ct*16 + l15][c*32 + lg*8]);

      #pragma unroll
      for (int bi = 0; bi < 2; ++bi) {       // 2 batches of 2 strips
        f32x4 z[2][2];
        #pragma unroll
        for (int sl = 0; sl < 2; ++sl) {
          z[sl][0] = f32x4{}; z[sl][1] = f32x4{};
          #pragma unroll
          for (int ks = 0; ks < 3; ++ks) {
            z[sl][0] = __builtin_amdgcn_mfma_f32_16x16x32_bf16(a1c[0][ks], hifr[bi*2+sl][ks], z[sl][0], 0, 0, 0);
            z[sl][1] = __builtin_amdgcn_mfma_f32_16x16x32_bf16(a1c[1][ks], hifr[bi*2+sl][ks], z[sl][1], 0, 0, 0);
          }
        }
        #pragma unroll
        for (int sl = 0; sl < 2; ++sl) {
          bf16x4 p0, p1;
          p0[0] = (__bf16)fmaxf(z[sl][0][0] + bc0.x, 0.f);
          p0[1] = (__bf16)fmaxf(z[sl][0][1] + bc0.y, 0.f);
          p0[2] = (__bf16)fmaxf(z[sl][0][2] + bc0.z, 0.f);
          p0[3] = (__bf16)fmaxf(z[sl][0][3] + bc0.w, 0.f);
          p1[0] = (__bf16)fmaxf(z[sl][1][0] + bc1.x, 0.f);
          p1[1] = (__bf16)fmaxf(z[sl][1][1] + bc1.y, 0.f);
          p1[2] = (__bf16)fmaxf(z[sl][1][2] + bc1.z, 0.f);
          p1[3] = (__bf16)fmaxf(z[sl][1][3] + bc1.w, 0.f);
          *reinterpret_cast<uint2*>(&Zb[w][sl][l15][lg*4])      = __builtin_bit_cast(uint2, p0);
          *reinterpret_cast<uint2*>(&Zb[w][sl][l15][16 + lg*4]) = __builtin_bit_cast(uint2, p1);
        }
        #pragma unroll
        for (int sl = 0; sl < 2; ++sl) {
          bf16x8 zf = *reinterpret_cast<const bf16x8*>(&Zb[w][sl][l15][lg*8]);
          #pragma unroll
          for (int ct = 0; ct < 6; ++ct)
            lgt[bi*2+sl][ct] = __builtin_amdgcn_mfma_f32_16x16x32_bf16(zf, b2fr[ct], lgt[bi*2+sl][ct], 0, 0, 0);
        }
      }
    }

    // ---- pass tail: per-column softmax partial over these 64 rows ----
    float lmv[4][4];
    #pragma unroll
    for (int s = 0; s < 4; ++s) {
      float4 mk = *reinterpret_cast<const float4*>(&mask[prow + s*16 + lg*4]);
      lmv[s][0] = __logf(mk.x); lmv[s][1] = __logf(mk.y);
      lmv[s][2] = __logf(mk.z); lmv[s][3] = __logf(mk.w);
    }
    float G[4][6][4];
    #pragma unroll
    for (int s = 0; s < 4; ++s)
      #pragma unroll
      for (int ct = 0; ct < 6; ++ct)
        #pragma unroll
        for (int j = 0; j < 4; ++j)
          G[s][ct][j] = b2f(Hi[(prow + s*16 + lg*4 + j)*Ncols + h*DH + ct*16 + l15]);

    #pragma unroll
    for (int ct = 0; ct < 6; ++ct) {
      float av[4][4];
      float m16 = -3.4e38f;
      #pragma unroll
      for (int s = 0; s < 4; ++s)
        #pragma unroll
        for (int j = 0; j < 4; ++j) {
          av[s][j] = lgt[s][ct][j] + b2s[ct] + lmv[s][j];
          m16 = fmaxf(m16, av[s][j]);
        }
      m16 = fmaxf(m16, __shfl_xor(m16, 16));
      m16 = fmaxf(m16, __shfl_xor(m16, 32));
      float l16 = 0.f, a16 = 0.f;
      #pragma unroll
      for (int s = 0; s < 4; ++s)
        #pragma unroll
        for (int j = 0; j < 4; ++j) {
          float p = __expf(av[s][j] - m16);
          l16 += p;
          a16 += p * G[s][ct][j];
        }
      l16 += __shfl_xor(l16, 16); l16 += __shfl_xor(l16, 32);
      a16 += __shfl_xor(a16, 16); a16 += __shfl_xor(a16, 32);
      // online merge into running (M,L,A)
      float M2 = fmaxf(Mr[ct], m16);
      float eo = __expf(Mr[ct] - M2), en = __expf(m16 - M2);
      Lr[ct] = Lr[ct]*eo + l16*en;
      Ar[ct] = Ar[ct]*eo + a16*en;
      Mr[ct] = M2;
    }
  }

  // ---- block-level merge of 4 wave partials -> output ----
  if (lane < 16) {
    #pragma unroll
    for (int ct = 0; ct < 6; ++ct) {
      mb[w][ct*16 + l15] = Mr[ct];
      lb[w][ct*16 + l15] = Lr[ct];
      ab[w][ct*16 + l15] = Ar[ct];
    }
  }
  __syncthreads();
  if (tid < 96) {
    float m = fmaxf(fmaxf(mb[0][tid], mb[1][tid]), fmaxf(mb[2][tid], mb[3][tid]));
    float l = 0.f, a = 0.f;
    #pragma unroll
    for (int q = 0; q < 4; ++q) {
      float sc = __expf(mb[q][tid] - m);
      l += lb[q][tid] * sc;
      a += ab[q][tid] * sc;
    }
    out[(size_t)b * Ncols + h*DH + tid] = a / l;
  }
}

// ---------------------------------------------------------------------------
// Workspace layout (bytes), total ~103 MB:
//   Hi  bf16 : 0           (100663296)
//   B1t bf16 : 100663296   (1179648)
//   W1t bf16 : 101842944   (589824)
//   W2t bf16 : 102432768   (589824)
// ---------------------------------------------------------------------------
extern "C" void kernel_launch(void* const* d_in, const int* in_sizes, int n_in,
                              void* d_out, int out_size, void* d_ws, size_t ws_size,
                              hipStream_t stream)
{
  const float* emb  = (const float*)d_in[0];
  const float* mask = (const float*)d_in[1];
  const float* Pw   = (const float*)d_in[2];
  const float* Pb   = (const float*)d_in[3];
  const float* W1w  = (const float*)d_in[4];
  const float* W1b  = (const float*)d_in[5];
  const float* W2w  = (const float*)d_in[6];
  const float* W2b  = (const float*)d_in[7];
  float* out = (float*)d_out;

  char* ws = (char*)d_ws;
  u16*   Hi  = (u16*)(ws);
  u16*   B1t = (u16*)(ws + 100663296ull);
  u16*   W1t = (u16*)(ws + 101842944ull);
  u16*   W2t = (u16*)(ws + 102432768ull);

  k_pack<<<dim3(4608), dim3(256), 0, stream>>>(Pw, W1w, W2w, B1t, W1t, W2t);
  k_gemm1<<<dim3(3072), dim3(256), 0, stream>>>(emb, B1t, Pb, Hi);
  k_ffn_pool<<<dim3(8, 32), dim3(256), 0, stream>>>(Hi, W1t, W2t, W1b, W2b, mask, out);
}

// Round 5
// 284.086 us; speedup vs baseline: 1.4272x; 1.0706x over previous
//
#include <hip/hip_runtime.h>
#include <cstdint>
#include <cstddef>

// Problem constants
#define Bsz   32
#define Ssz   2048
#define Tsz   768
#define NH    8
#define DH    96
#define DHID  384
#define Ncols (NH*DH)       // 768

using u16 = unsigned short;
typedef __bf16 bf16x8 __attribute__((ext_vector_type(8)));
typedef __bf16 bf16x4 __attribute__((ext_vector_type(4)));
typedef float  f32x4  __attribute__((ext_vector_type(4)));

__device__ __forceinline__ u16 f2bn(float f) {
  __bf16 h = (__bf16)f;
  return __builtin_bit_cast(u16, h);
}
__device__ __forceinline__ float b2f(u16 u) {
  return __builtin_bit_cast(float, (uint32_t)u << 16);
}

// async global->LDS, 16B per lane; LDS dest = wave-uniform base + lane*16
typedef const __attribute__((address_space(1))) void* gas_t;
typedef __attribute__((address_space(3))) void* las_t;
__device__ __forceinline__ void gload16(const void* g, void* s) {
  __builtin_amdgcn_global_load_lds((gas_t)g, (las_t)s, 16, 0, 0);
}

// ---------------------------------------------------------------------------
// Kernel 1: pack weights to bf16, transposed so MFMA frags are contiguous in K
//   B1t[n][k]  (n = h*96+d, k in [0,768))  <- P_w[h][k][d]
//   W1t[h][n][k] (n<384, k<96)             <- W1_w[h][k][n]
//   W2t[h][n][k] (n<96,  k<384)            <- W2_w[h][k][n]
// ---------------------------------------------------------------------------
__global__ __launch_bounds__(256) void k_pack(const float* __restrict__ Pw,
    const float* __restrict__ W1w, const float* __restrict__ W2w,
    u16* __restrict__ B1t, u16* __restrict__ W1t, u16* __restrict__ W2t)
{
  int i = blockIdx.x * 256 + threadIdx.x;
  if (i < 589824) {
    int n = i / 768, k = i % 768;
    int h = n / 96, d = n % 96;
    B1t[i] = f2bn(Pw[(size_t)h*73728 + (size_t)k*96 + d]);
  } else if (i < 589824 + 294912) {
    int j = i - 589824;
    int h = j / 36864, r = j % 36864;
    int n = r / 96, k = r % 96;
    W1t[j] = f2bn(W1w[(size_t)h*36864 + (size_t)k*384 + n]);
  } else if (i < 589824 + 2*294912) {
    int q = i - 589824 - 294912;
    int h = q / 36864, r = q % 36864;
    int n = r / 384, k = r % 384;
    W2t[q] = f2bn(W2w[(size_t)h*36864 + (size_t)k*96 + n]);
  }
}

// ---------------------------------------------------------------------------
// Kernel 2 (v2, m97-style): Hi[65536][768] bf16 = emb @ B1 + P_b
// 128x128 tile, BK=64, 4 waves (2x2). A staged as RAW fp32 via global_load_lds
// (convert after ds_read); B staged bf16 via global_load_lds. LDS linear in
// lane order; XOR-chunk swizzle applied on the per-lane GLOBAL src address and
// again on the ds_read address (rule #21: both-sides-or-neither).
//   A: 256B/row = 16 chunks; phys_chunk = logical ^ (row&15)
//   B: 128B/row =  8 chunks; phys_chunk = logical ^ (row&7)
// ---------------------------------------------------------------------------
__global__ __launch_bounds__(256) void k_gemm1(const float* __restrict__ emb,
    const u16* __restrict__ B1t, const float* __restrict__ Pb, u16* __restrict__ Hi)
{
  __shared__ float As[128*64];   // 32 KB fp32 A tile (swizzled chunks)
  __shared__ u16   Bs[128*64];   // 16 KB bf16 B tile (swizzled chunks)
  const int tid  = threadIdx.x;
  const int lane = tid & 63;
  const int w    = tid >> 6;
  const int wr = w >> 1, wc = w & 1;
  const int L = blockIdx.x;                 // 0..3071, XCD-chunked swizzle
  const int widx = (L & 7) * 384 + (L >> 3);
  const int bm = widx / 6, bn = widx % 6;
  const int l15 = lane & 15, lg = lane >> 4;

  // staging lane geometry
  const int arow_in = lane >> 4;   // A: 4 rows per 1KB issue (16 chunks/row)
  const int achunk  = lane & 15;   // physical chunk this lane fills
  const int brow_in = lane >> 3;   // B: 8 rows per 1KB issue (8 chunks/row)
  const int bchunk  = lane & 7;

  f32x4 acc[4][4] = {};

  for (int kt = 0; kt < 12; ++kt) {
    const int k0 = kt * 64;
    // stage A: 128 rows x 64 fp32, 8 issues/wave (1KB each)
    #pragma unroll
    for (int i = 0; i < 8; ++i) {
      const int row = (w*8 + i)*4 + arow_in;
      const int lc  = achunk ^ (row & 15);       // inverse-swizzled source chunk
      gload16(emb + (size_t)(bm*128 + row)*Tsz + k0 + lc*4,
              &As[(w*8 + i)*256]);
    }
    // stage B: 128 rows x 64 bf16, 4 issues/wave
    #pragma unroll
    for (int i = 0; i < 4; ++i) {
      const int row = (w*4 + i)*8 + brow_in;     // row&7 == brow_in
      const int lc  = bchunk ^ brow_in;
      gload16(B1t + (size_t)(bn*128 + row)*Tsz + k0 + lc*8,
              &Bs[(w*4 + i)*512]);
    }
    __syncthreads();   // compiler drains vmcnt before barrier

    // B fragments (swizzled read): logical chunk kk*4+lg -> phys ^ (row&7)
    bf16x8 b[4][2];
    #pragma unroll
    for (int c = 0; c < 4; ++c) {
      const int Rb = wc*64 + c*16 + l15;
      #pragma unroll
      for (int kk = 0; kk < 2; ++kk)
        b[c][kk] = *reinterpret_cast<const bf16x8*>(
            &Bs[Rb*64 + (((kk*4 + lg) ^ (l15 & 7))*8)]);
    }
    // A fragments: two fp32 chunks per frag, convert to bf16x8, MFMA
    #pragma unroll
    for (int r = 0; r < 4; ++r) {
      const int R = wr*64 + r*16 + l15;          // R&15 == l15
      #pragma unroll
      for (int kk = 0; kk < 2; ++kk) {
        const int c0 = kk*8 + lg*2;
        f32x4 fa0 = *reinterpret_cast<const f32x4*>(&As[R*64 + ((c0    ) ^ l15)*4]);
        f32x4 fa1 = *reinterpret_cast<const f32x4*>(&As[R*64 + ((c0 + 1) ^ l15)*4]);
        bf16x8 af;
        af[0] = (__bf16)fa0[0]; af[1] = (__bf16)fa0[1];
        af[2] = (__bf16)fa0[2]; af[3] = (__bf16)fa0[3];
        af[4] = (__bf16)fa1[0]; af[5] = (__bf16)fa1[1];
        af[6] = (__bf16)fa1[2]; af[7] = (__bf16)fa1[3];
        #pragma unroll
        for (int c = 0; c < 4; ++c)
          acc[r][c] = __builtin_amdgcn_mfma_f32_16x16x32_bf16(af, b[c][kk], acc[r][c], 0, 0, 0);
      }
    }
    __syncthreads();
  }
  // epilogue: bias + bf16 store (C layout: col=lane&15, row=(lane>>4)*4+j)
  #pragma unroll
  for (int c = 0; c < 4; ++c) {
    int col = bn*128 + wc*64 + c*16 + l15;
    float bias = Pb[col];
    #pragma unroll
    for (int r = 0; r < 4; ++r) {
      int row0 = bm*128 + wr*64 + r*16 + lg*4;
      #pragma unroll
      for (int j = 0; j < 4; ++j)
        Hi[(size_t)(row0 + j)*Ncols + col] = f2bn(acc[r][c][j] + bias);
    }
  }
}

// ---------------------------------------------------------------------------
// Kernel 3 (v4, unchanged): persistent per-(h,b) block, fused FFN + pool.
// ---------------------------------------------------------------------------
__global__ __launch_bounds__(256, 1) void k_ffn_pool(
    const u16* __restrict__ Hi, const u16* __restrict__ W1t, const u16* __restrict__ W2t,
    const float* __restrict__ b1, const float* __restrict__ b2v, const float* __restrict__ mask,
    float* __restrict__ out)
{
  __shared__ u16 W2s[96][392];              // 74.5 KB
  __shared__ u16 Zb[4][2][16][40];          // 10 KB
  __shared__ float mb[4][96], lb[4][96], ab[4][96];  // 4.5 KB

  const int tid = threadIdx.x, lane = tid & 63, w = tid >> 6;
  const int l15 = lane & 15, lg = lane >> 4;
  const int h = blockIdx.x, b = blockIdx.y;

  const u16* W1h = W1t + (size_t)h * DHID * DH;
  const u16* W2h = W2t + (size_t)h * DH * DHID;
  const float* b1h = b1 + h * DHID;

  for (int i = tid; i < 96*48; i += 256) {
    int r = i / 48, g = i % 48;
    uint4 v = *reinterpret_cast<const uint4*>(W2h + (size_t)r*DHID + g*8);
    *reinterpret_cast<uint4*>(&W2s[r][g*8]) = v;
  }
  __syncthreads();

  float b2s[6];
  #pragma unroll
  for (int ct = 0; ct < 6; ++ct) b2s[ct] = b2v[h*DH + ct*16 + l15];

  float Mr[6], Lr[6], Ar[6];
  #pragma unroll
  for (int ct = 0; ct < 6; ++ct) { Mr[ct] = -3.4e38f; Lr[ct] = 0.f; Ar[ct] = 0.f; }

  #pragma unroll 1
  for (int pass = 0; pass < 8; ++pass) {
    const size_t prow = (size_t)b*Ssz + (size_t)w*512 + (size_t)pass*64;

    bf16x8 hifr[4][3];
    #pragma unroll
    for (int s = 0; s < 4; ++s)
      #pragma unroll
      for (int ks = 0; ks < 3; ++ks)
        hifr[s][ks] = *reinterpret_cast<const bf16x8*>(
            Hi + (prow + s*16 + l15)*Ncols + h*DH + ks*32 + lg*8);

    f32x4 lgt[4][6] = {};

    #pragma unroll 2
    for (int c = 0; c < 12; ++c) {
      bf16x8 a1c[2][3];
      #pragma unroll
      for (int t = 0; t < 2; ++t)
        #pragma unroll
        for (int ks = 0; ks < 3; ++ks)
          a1c[t][ks] = *reinterpret_cast<const bf16x8*>(
              W1h + (size_t)(c*32 + t*16 + l15)*DH + ks*32 + lg*8);
      float4 bc0 = *reinterpret_cast<const float4*>(b1h + c*32 + lg*4);
      float4 bc1 = *reinterpret_cast<const float4*>(b1h + c*32 + 16 + lg*4);
      bf16x8 b2fr[6];
      #pragma unroll
      for (int ct = 0; ct < 6; ++ct)
        b2fr[ct] = *reinterpret_cast<const bf16x8*>(&W2s[ct*16 + l15][c*32 + lg*8]);

      #pragma unroll
      for (int bi = 0; bi < 2; ++bi) {
        f32x4 z[2][2];
        #pragma unroll
        for (int sl = 0; sl < 2; ++sl) {
          z[sl][0] = f32x4{}; z[sl][1] = f32x4{};
          #pragma unroll
          for (int ks = 0; ks < 3; ++ks) {
            z[sl][0] = __builtin_amdgcn_mfma_f32_16x16x32_bf16(a1c[0][ks], hifr[bi*2+sl][ks], z[sl][0], 0, 0, 0);
            z[sl][1] = __builtin_amdgcn_mfma_f32_16x16x32_bf16(a1c[1][ks], hifr[bi*2+sl][ks], z[sl][1], 0, 0, 0);
          }
        }
        #pragma unroll
        for (int sl = 0; sl < 2; ++sl) {
          bf16x4 p0, p1;
          p0[0] = (__bf16)fmaxf(z[sl][0][0] + bc0.x, 0.f);
          p0[1] = (__bf16)fmaxf(z[sl][0][1] + bc0.y, 0.f);
          p0[2] = (__bf16)fmaxf(z[sl][0][2] + bc0.z, 0.f);
          p0[3] = (__bf16)fmaxf(z[sl][0][3] + bc0.w, 0.f);
          p1[0] = (__bf16)fmaxf(z[sl][1][0] + bc1.x, 0.f);
          p1[1] = (__bf16)fmaxf(z[sl][1][1] + bc1.y, 0.f);
          p1[2] = (__bf16)fmaxf(z[sl][1][2] + bc1.z, 0.f);
          p1[3] = (__bf16)fmaxf(z[sl][1][3] + bc1.w, 0.f);
          *reinterpret_cast<uint2*>(&Zb[w][sl][l15][lg*4])      = __builtin_bit_cast(uint2, p0);
          *reinterpret_cast<uint2*>(&Zb[w][sl][l15][16 + lg*4]) = __builtin_bit_cast(uint2, p1);
        }
        #pragma unroll
        for (int sl = 0; sl < 2; ++sl) {
          bf16x8 zf = *reinterpret_cast<const bf16x8*>(&Zb[w][sl][l15][lg*8]);
          #pragma unroll
          for (int ct = 0; ct < 6; ++ct)
            lgt[bi*2+sl][ct] = __builtin_amdgcn_mfma_f32_16x16x32_bf16(zf, b2fr[ct], lgt[bi*2+sl][ct], 0, 0, 0);
        }
      }
    }

    float lmv[4][4];
    #pragma unroll
    for (int s = 0; s < 4; ++s) {
      float4 mk = *reinterpret_cast<const float4*>(&mask[prow + s*16 + lg*4]);
      lmv[s][0] = __logf(mk.x); lmv[s][1] = __logf(mk.y);
      lmv[s][2] = __logf(mk.z); lmv[s][3] = __logf(mk.w);
    }
    float G[4][6][4];
    #pragma unroll
    for (int s = 0; s < 4; ++s)
      #pragma unroll
      for (int ct = 0; ct < 6; ++ct)
        #pragma unroll
        for (int j = 0; j < 4; ++j)
          G[s][ct][j] = b2f(Hi[(prow + s*16 + lg*4 + j)*Ncols + h*DH + ct*16 + l15]);

    #pragma unroll
    for (int ct = 0; ct < 6; ++ct) {
      float av[4][4];
      float m16 = -3.4e38f;
      #pragma unroll
      for (int s = 0; s < 4; ++s)
        #pragma unroll
        for (int j = 0; j < 4; ++j) {
          av[s][j] = lgt[s][ct][j] + b2s[ct] + lmv[s][j];
          m16 = fmaxf(m16, av[s][j]);
        }
      m16 = fmaxf(m16, __shfl_xor(m16, 16));
      m16 = fmaxf(m16, __shfl_xor(m16, 32));
      float l16 = 0.f, a16 = 0.f;
      #pragma unroll
      for (int s = 0; s < 4; ++s)
        #pragma unroll
        for (int j = 0; j < 4; ++j) {
          float p = __expf(av[s][j] - m16);
          l16 += p;
          a16 += p * G[s][ct][j];
        }
      l16 += __shfl_xor(l16, 16); l16 += __shfl_xor(l16, 32);
      a16 += __shfl_xor(a16, 16); a16 += __shfl_xor(a16, 32);
      float M2 = fmaxf(Mr[ct], m16);
      float eo = __expf(Mr[ct] - M2), en = __expf(m16 - M2);
      Lr[ct] = Lr[ct]*eo + l16*en;
      Ar[ct] = Ar[ct]*eo + a16*en;
      Mr[ct] = M2;
    }
  }

  if (lane < 16) {
    #pragma unroll
    for (int ct = 0; ct < 6; ++ct) {
      mb[w][ct*16 + l15] = Mr[ct];
      lb[w][ct*16 + l15] = Lr[ct];
      ab[w][ct*16 + l15] = Ar[ct];
    }
  }
  __syncthreads();
  if (tid < 96) {
    float m = fmaxf(fmaxf(mb[0][tid], mb[1][tid]), fmaxf(mb[2][tid], mb[3][tid]));
    float l = 0.f, a = 0.f;
    #pragma unroll
    for (int q = 0; q < 4; ++q) {
      float sc = __expf(mb[q][tid] - m);
      l += lb[q][tid] * sc;
      a += ab[q][tid] * sc;
    }
    out[(size_t)b * Ncols + h*DH + tid] = a / l;
  }
}

// ---------------------------------------------------------------------------
// Workspace layout (bytes), total ~103 MB:
//   Hi  bf16 : 0           (100663296)
//   B1t bf16 : 100663296   (1179648)
//   W1t bf16 : 101842944   (589824)
//   W2t bf16 : 102432768   (589824)
// ---------------------------------------------------------------------------
extern "C" void kernel_launch(void* const* d_in, const int* in_sizes, int n_in,
                              void* d_out, int out_size, void* d_ws, size_t ws_size,
                              hipStream_t stream)
{
  const float* emb  = (const float*)d_in[0];
  const float* mask = (const float*)d_in[1];
  const float* Pw   = (const float*)d_in[2];
  const float* Pb   = (const float*)d_in[3];
  const float* W1w  = (const float*)d_in[4];
  const float* W1b  = (const float*)d_in[5];
  const float* W2w  = (const float*)d_in[6];
  const float* W2b  = (const float*)d_in[7];
  float* out = (float*)d_out;

  char* ws = (char*)d_ws;
  u16*   Hi  = (u16*)(ws);
  u16*   B1t = (u16*)(ws + 100663296ull);
  u16*   W1t = (u16*)(ws + 101842944ull);
  u16*   W2t = (u16*)(ws + 102432768ull);

  k_pack<<<dim3(4608), dim3(256), 0, stream>>>(Pw, W1w, W2w, B1t, W1t, W2t);
  k_gemm1<<<dim3(3072), dim3(256), 0, stream>>>(emb, B1t, Pb, Hi);
  k_ffn_pool<<<dim3(8, 32), dim3(256), 0, stream>>>(Hi, W1t, W2t, W1b, W2b, mask, out);
}

// Round 6
// 284.043 us; speedup vs baseline: 1.4274x; 1.0002x over previous
//
#include <hip/hip_runtime.h>
#include <cstdint>
#include <cstddef>

// Problem constants
#define Bsz   32
#define Ssz   2048
#define Tsz   768
#define NH    8
#define DH    96
#define DHID  384
#define Ncols (NH*DH)       // 768

using u16 = unsigned short;
typedef __bf16 bf16x8 __attribute__((ext_vector_type(8)));
typedef __bf16 bf16x4 __attribute__((ext_vector_type(4)));
typedef float  f32x4  __attribute__((ext_vector_type(4)));

__device__ __forceinline__ u16 f2bn(float f) {
  __bf16 h = (__bf16)f;
  return __builtin_bit_cast(u16, h);
}
__device__ __forceinline__ float b2f(u16 u) {
  return __builtin_bit_cast(float, (uint32_t)u << 16);
}

// async global->LDS, 16B per lane; LDS dest = wave-uniform base + lane*16
typedef const __attribute__((address_space(1))) void* gas_t;
typedef __attribute__((address_space(3))) void* las_t;
__device__ __forceinline__ void gload16(const void* g, void* s) {
  __builtin_amdgcn_global_load_lds((gas_t)g, (las_t)s, 16, 0, 0);
}

// ---------------------------------------------------------------------------
// Kernel 1: pack weights to bf16 (transposed, K-contiguous)  [unchanged]
// ---------------------------------------------------------------------------
__global__ __launch_bounds__(256) void k_pack(const float* __restrict__ Pw,
    const float* __restrict__ W1w, const float* __restrict__ W2w,
    u16* __restrict__ B1t, u16* __restrict__ W1t, u16* __restrict__ W2t)
{
  int i = blockIdx.x * 256 + threadIdx.x;
  if (i < 589824) {
    int n = i / 768, k = i % 768;
    int h = n / 96, d = n % 96;
    B1t[i] = f2bn(Pw[(size_t)h*73728 + (size_t)k*96 + d]);
  } else if (i < 589824 + 294912) {
    int j = i - 589824;
    int h = j / 36864, r = j % 36864;
    int n = r / 96, k = r % 96;
    W1t[j] = f2bn(W1w[(size_t)h*36864 + (size_t)k*384 + n]);
  } else if (i < 589824 + 2*294912) {
    int q = i - 589824 - 294912;
    int h = q / 36864, r = q % 36864;
    int n = r / 384, k = r % 384;
    W2t[q] = f2bn(W2w[(size_t)h*36864 + (size_t)k*96 + n]);
  }
}

// ---------------------------------------------------------------------------
// Kernel 2 (v3): Hi = emb @ B1 + P_b.  BM=256, BN=128, BK=64, 4 waves (2x2),
// wave tile 128x64 (acc 8x4) -> 2.67 MFMA per ds_read_b128 (was 1.33).
// A: reg-staged fp32->bf16 (cvt_pk) with XOR-chunk-swizzled ds_write_b128.
// B: bf16 via global_load_lds, source-swizzled (rule #21), LDS linear.
// Both LDS tiles: row = 128B = 8 chunks of 16B; phys_chunk = logical ^ (row&7).
// ---------------------------------------------------------------------------
__global__ __launch_bounds__(256, 2) void k_gemm1(const float* __restrict__ emb,
    const u16* __restrict__ B1t, const float* __restrict__ Pb, u16* __restrict__ Hi)
{
  __shared__ u16 As[256*64];   // 32 KB bf16 A tile (swizzled chunks)
  __shared__ u16 Bs[128*64];   // 16 KB bf16 B tile (swizzled chunks)
  const int tid  = threadIdx.x;
  const int lane = tid & 63;
  const int w    = tid >> 6;
  const int wr = w >> 1, wc = w & 1;            // wave tile: rows wr*128, cols wc*64
  const int L = blockIdx.x;                     // 0..1535, XCD-chunked swizzle
  const int widx = (L & 7) * 192 + (L >> 3);
  const int bm = widx / 6, bn = widx % 6;
  const int l15 = lane & 15, lg = lane >> 4;

  // A staging geometry: 8 rows x 8 chunks per wave-instr
  const int srow   = lane >> 3;     // 0..7
  const int schunk = lane & 7;      // logical 16B-bf16 chunk (8 bf16 = 32B fp32)
  // B staging geometry (gload16): 8 rows x 8 chunks per issue
  const int brow_in = lane >> 3;
  const int bchunk  = lane & 7;

  f32x4 acc[8][4] = {};

  for (int kt = 0; kt < 12; ++kt) {
    const int k0 = kt * 64;
    // issue B async first: 128 rows x 64 bf16, 4 issues/wave (1KB each)
    #pragma unroll
    for (int i = 0; i < 4; ++i) {
      const int row = (w*4 + i)*8 + brow_in;     // row&7 == brow_in
      const int lc  = bchunk ^ brow_in;          // inverse-swizzled source chunk
      gload16(B1t + (size_t)(bn*128 + row)*Tsz + k0 + lc*8,
              &Bs[(w*4 + i)*512]);
    }
    // reg-stage A: 256 rows x 64 fp32 -> bf16; wave w owns rows w*64..w*64+63
    #pragma unroll
    for (int i = 0; i < 8; ++i) {
      const int row = w*64 + i*8 + srow;
      const float* src = emb + (size_t)(bm*256 + row)*Tsz + k0 + schunk*8;
      float4 v0 = *reinterpret_cast<const float4*>(src);
      float4 v1 = *reinterpret_cast<const float4*>(src + 4);
      bf16x8 af;
      af[0] = (__bf16)v0.x; af[1] = (__bf16)v0.y; af[2] = (__bf16)v0.z; af[3] = (__bf16)v0.w;
      af[4] = (__bf16)v1.x; af[5] = (__bf16)v1.y; af[6] = (__bf16)v1.z; af[7] = (__bf16)v1.w;
      const int phys = schunk ^ (row & 7);
      *reinterpret_cast<bf16x8*>(&As[row*64 + phys*8]) = af;
    }
    __syncthreads();   // drains vmcnt + lgkmcnt

    #pragma unroll
    for (int kk = 0; kk < 2; ++kk) {
      const int clog = kk*4 + lg;                // logical 16B chunk in row
      bf16x8 b[4];
      #pragma unroll
      for (int c = 0; c < 4; ++c) {
        const int Rb = wc*64 + c*16 + l15;
        b[c] = *reinterpret_cast<const bf16x8*>(&Bs[Rb*64 + (clog ^ (Rb & 7))*8]);
      }
      bf16x8 a[8];
      #pragma unroll
      for (int m = 0; m < 8; ++m) {
        const int R = wr*128 + m*16 + l15;
        a[m] = *reinterpret_cast<const bf16x8*>(&As[R*64 + (clog ^ (R & 7))*8]);
      }
      #pragma unroll
      for (int m = 0; m < 8; ++m)
        #pragma unroll
        for (int c = 0; c < 4; ++c)
          acc[m][c] = __builtin_amdgcn_mfma_f32_16x16x32_bf16(a[m], b[c], acc[m][c], 0, 0, 0);
    }
    __syncthreads();
  }
  // epilogue: bias + bf16 store (C layout: col=lane&15, row=(lane>>4)*4+j)
  #pragma unroll
  for (int c = 0; c < 4; ++c) {
    int col = bn*128 + wc*64 + c*16 + l15;
    float bias = Pb[col];
    #pragma unroll
    for (int m = 0; m < 8; ++m) {
      int row0 = bm*256 + wr*128 + m*16 + lg*4;
      #pragma unroll
      for (int j = 0; j < 4; ++j)
        Hi[(size_t)(row0 + j)*Ncols + col] = f2bn(acc[m][c][j] + bias);
    }
  }
}

// ---------------------------------------------------------------------------
// Kernel 3 (v4, unchanged): persistent per-(h,b) block, fused FFN + pool.
// ---------------------------------------------------------------------------
__global__ __launch_bounds__(256, 1) void k_ffn_pool(
    const u16* __restrict__ Hi, const u16* __restrict__ W1t, const u16* __restrict__ W2t,
    const float* __restrict__ b1, const float* __restrict__ b2v, const float* __restrict__ mask,
    float* __restrict__ out)
{
  __shared__ u16 W2s[96][392];              // 74.5 KB
  __shared__ u16 Zb[4][2][16][40];          // 10 KB
  __shared__ float mb[4][96], lb[4][96], ab[4][96];  // 4.5 KB

  const int tid = threadIdx.x, lane = tid & 63, w = tid >> 6;
  const int l15 = lane & 15, lg = lane >> 4;
  const int h = blockIdx.x, b = blockIdx.y;

  const u16* W1h = W1t + (size_t)h * DHID * DH;
  const u16* W2h = W2t + (size_t)h * DH * DHID;
  const float* b1h = b1 + h * DHID;

  for (int i = tid; i < 96*48; i += 256) {
    int r = i / 48, g = i % 48;
    uint4 v = *reinterpret_cast<const uint4*>(W2h + (size_t)r*DHID + g*8);
    *reinterpret_cast<uint4*>(&W2s[r][g*8]) = v;
  }
  __syncthreads();

  float b2s[6];
  #pragma unroll
  for (int ct = 0; ct < 6; ++ct) b2s[ct] = b2v[h*DH + ct*16 + l15];

  float Mr[6], Lr[6], Ar[6];
  #pragma unroll
  for (int ct = 0; ct < 6; ++ct) { Mr[ct] = -3.4e38f; Lr[ct] = 0.f; Ar[ct] = 0.f; }

  #pragma unroll 1
  for (int pass = 0; pass < 8; ++pass) {
    const size_t prow = (size_t)b*Ssz + (size_t)w*512 + (size_t)pass*64;

    bf16x8 hifr[4][3];
    #pragma unroll
    for (int s = 0; s < 4; ++s)
      #pragma unroll
      for (int ks = 0; ks < 3; ++ks)
        hifr[s][ks] = *reinterpret_cast<const bf16x8*>(
            Hi + (prow + s*16 + l15)*Ncols + h*DH + ks*32 + lg*8);

    f32x4 lgt[4][6] = {};

    #pragma unroll 2
    for (int c = 0; c < 12; ++c) {
      bf16x8 a1c[2][3];
      #pragma unroll
      for (int t = 0; t < 2; ++t)
        #pragma unroll
        for (int ks = 0; ks < 3; ++ks)
          a1c[t][ks] = *reinterpret_cast<const bf16x8*>(
              W1h + (size_t)(c*32 + t*16 + l15)*DH + ks*32 + lg*8);
      float4 bc0 = *reinterpret_cast<const float4*>(b1h + c*32 + lg*4);
      float4 bc1 = *reinterpret_cast<const float4*>(b1h + c*32 + 16 + lg*4);
      bf16x8 b2fr[6];
      #pragma unroll
      for (int ct = 0; ct < 6; ++ct)
        b2fr[ct] = *reinterpret_cast<const bf16x8*>(&W2s[ct*16 + l15][c*32 + lg*8]);

      #pragma unroll
      for (int bi = 0; bi < 2; ++bi) {
        f32x4 z[2][2];
        #pragma unroll
        for (int sl = 0; sl < 2; ++sl) {
          z[sl][0] = f32x4{}; z[sl][1] = f32x4{};
          #pragma unroll
          for (int ks = 0; ks < 3; ++ks) {
            z[sl][0] = __builtin_amdgcn_mfma_f32_16x16x32_bf16(a1c[0][ks], hifr[bi*2+sl][ks], z[sl][0], 0, 0, 0);
            z[sl][1] = __builtin_amdgcn_mfma_f32_16x16x32_bf16(a1c[1][ks], hifr[bi*2+sl][ks], z[sl][1], 0, 0, 0);
          }
        }
        #pragma unroll
        for (int sl = 0; sl < 2; ++sl) {
          bf16x4 p0, p1;
          p0[0] = (__bf16)fmaxf(z[sl][0][0] + bc0.x, 0.f);
          p0[1] = (__bf16)fmaxf(z[sl][0][1] + bc0.y, 0.f);
          p0[2] = (__bf16)fmaxf(z[sl][0][2] + bc0.z, 0.f);
          p0[3] = (__bf16)fmaxf(z[sl][0][3] + bc0.w, 0.f);
          p1[0] = (__bf16)fmaxf(z[sl][1][0] + bc1.x, 0.f);
          p1[1] = (__bf16)fmaxf(z[sl][1][1] + bc1.y, 0.f);
          p1[2] = (__bf16)fmaxf(z[sl][1][2] + bc1.z, 0.f);
          p1[3] = (__bf16)fmaxf(z[sl][1][3] + bc1.w, 0.f);
          *reinterpret_cast<uint2*>(&Zb[w][sl][l15][lg*4])      = __builtin_bit_cast(uint2, p0);
          *reinterpret_cast<uint2*>(&Zb[w][sl][l15][16 + lg*4]) = __builtin_bit_cast(uint2, p1);
        }
        #pragma unroll
        for (int sl = 0; sl < 2; ++sl) {
          bf16x8 zf = *reinterpret_cast<const bf16x8*>(&Zb[w][sl][l15][lg*8]);
          #pragma unroll
          for (int ct = 0; ct < 6; ++ct)
            lgt[bi*2+sl][ct] = __builtin_amdgcn_mfma_f32_16x16x32_bf16(zf, b2fr[ct], lgt[bi*2+sl][ct], 0, 0, 0);
        }
      }
    }

    float lmv[4][4];
    #pragma unroll
    for (int s = 0; s < 4; ++s) {
      float4 mk = *reinterpret_cast<const float4*>(&mask[prow + s*16 + lg*4]);
      lmv[s][0] = __logf(mk.x); lmv[s][1] = __logf(mk.y);
      lmv[s][2] = __logf(mk.z); lmv[s][3] = __logf(mk.w);
    }
    float G[4][6][4];
    #pragma unroll
    for (int s = 0; s < 4; ++s)
      #pragma unroll
      for (int ct = 0; ct < 6; ++ct)
        #pragma unroll
        for (int j = 0; j < 4; ++j)
          G[s][ct][j] = b2f(Hi[(prow + s*16 + lg*4 + j)*Ncols + h*DH + ct*16 + l15]);

    #pragma unroll
    for (int ct = 0; ct < 6; ++ct) {
      float av[4][4];
      float m16 = -3.4e38f;
      #pragma unroll
      for (int s = 0; s < 4; ++s)
        #pragma unroll
        for (int j = 0; j < 4; ++j) {
          av[s][j] = lgt[s][ct][j] + b2s[ct] + lmv[s][j];
          m16 = fmaxf(m16, av[s][j]);
        }
      m16 = fmaxf(m16, __shfl_xor(m16, 16));
      m16 = fmaxf(m16, __shfl_xor(m16, 32));
      float l16 = 0.f, a16 = 0.f;
      #pragma unroll
      for (int s = 0; s < 4; ++s)
        #pragma unroll
        for (int j = 0; j < 4; ++j) {
          float p = __expf(av[s][j] - m16);
          l16 += p;
          a16 += p * G[s][ct][j];
        }
      l16 += __shfl_xor(l16, 16); l16 += __shfl_xor(l16, 32);
      a16 += __shfl_xor(a16, 16); a16 += __shfl_xor(a16, 32);
      float M2 = fmaxf(Mr[ct], m16);
      float eo = __expf(Mr[ct] - M2), en = __expf(m16 - M2);
      Lr[ct] = Lr[ct]*eo + l16*en;
      Ar[ct] = Ar[ct]*eo + a16*en;
      Mr[ct] = M2;
    }
  }

  if (lane < 16) {
    #pragma unroll
    for (int ct = 0; ct < 6; ++ct) {
      mb[w][ct*16 + l15] = Mr[ct];
      lb[w][ct*16 + l15] = Lr[ct];
      ab[w][ct*16 + l15] = Ar[ct];
    }
  }
  __syncthreads();
  if (tid < 96) {
    float m = fmaxf(fmaxf(mb[0][tid], mb[1][tid]), fmaxf(mb[2][tid], mb[3][tid]));
    float l = 0.f, a = 0.f;
    #pragma unroll
    for (int q = 0; q < 4; ++q) {
      float sc = __expf(mb[q][tid] - m);
      l += lb[q][tid] * sc;
      a += ab[q][tid] * sc;
    }
    out[(size_t)b * Ncols + h*DH + tid] = a / l;
  }
}

// ---------------------------------------------------------------------------
// Workspace layout (bytes), total ~103 MB:
//   Hi  bf16 : 0           (100663296)
//   B1t bf16 : 100663296   (1179648)
//   W1t bf16 : 101842944   (589824)
//   W2t bf16 : 102432768   (589824)
// ---------------------------------------------------------------------------
extern "C" void kernel_launch(void* const* d_in, const int* in_sizes, int n_in,
                              void* d_out, int out_size, void* d_ws, size_t ws_size,
                              hipStream_t stream)
{
  const float* emb  = (const float*)d_in[0];
  const float* mask = (const float*)d_in[1];
  const float* Pw   = (const float*)d_in[2];
  const float* Pb   = (const float*)d_in[3];
  const float* W1w  = (const float*)d_in[4];
  const float* W1b  = (const float*)d_in[5];
  const float* W2w  = (const float*)d_in[6];
  const float* W2b  = (const float*)d_in[7];
  float* out = (float*)d_out;

  char* ws = (char*)d_ws;
  u16*   Hi  = (u16*)(ws);
  u16*   B1t = (u16*)(ws + 100663296ull);
  u16*   W1t = (u16*)(ws + 101842944ull);
  u16*   W2t = (u16*)(ws + 102432768ull);

  k_pack<<<dim3(4608), dim3(256), 0, stream>>>(Pw, W1w, W2w, B1t, W1t, W2t);
  k_gemm1<<<dim3(1536), dim3(256), 0, stream>>>(emb, B1t, Pb, Hi);
  k_ffn_pool<<<dim3(8, 32), dim3(256), 0, stream>>>(Hi, W1t, W2t, W1b, W2b, mask, out);
}

// Round 7
// 274.502 us; speedup vs baseline: 1.4770x; 1.0348x over previous
//
#include <hip/hip_runtime.h>
#include <cstdint>
#include <cstddef>

// Problem constants
#define Bsz   32
#define Ssz   2048
#define Tsz   768
#define NH    8
#define DH    96
#define DHID  384
#define Ncols (NH*DH)       // 768

using u16 = unsigned short;
typedef __bf16 bf16x8 __attribute__((ext_vector_type(8)));
typedef __bf16 bf16x4 __attribute__((ext_vector_type(4)));
typedef float  f32x4  __attribute__((ext_vector_type(4)));

__device__ __forceinline__ u16 f2bn(float f) {
  __bf16 h = (__bf16)f;
  return __builtin_bit_cast(u16, h);
}
__device__ __forceinline__ float b2f(u16 u) {
  return __builtin_bit_cast(float, (uint32_t)u << 16);
}

// ---------------------------------------------------------------------------
// Kernel 1: pack weights to bf16 (transposed, K-contiguous)  [unchanged]
// ---------------------------------------------------------------------------
__global__ __launch_bounds__(256) void k_pack(const float* __restrict__ Pw,
    const float* __restrict__ W1w, const float* __restrict__ W2w,
    u16* __restrict__ B1t, u16* __restrict__ W1t, u16* __restrict__ W2t)
{
  int i = blockIdx.x * 256 + threadIdx.x;
  if (i < 589824) {
    int n = i / 768, k = i % 768;
    int h = n / 96, d = n % 96;
    B1t[i] = f2bn(Pw[(size_t)h*73728 + (size_t)k*96 + d]);
  } else if (i < 589824 + 294912) {
    int j = i - 589824;
    int h = j / 36864, r = j % 36864;
    int n = r / 96, k = r % 96;
    W1t[j] = f2bn(W1w[(size_t)h*36864 + (size_t)k*384 + n]);
  } else if (i < 589824 + 2*294912) {
    int q = i - 589824 - 294912;
    int h = q / 36864, r = q % 36864;
    int n = r / 384, k = r % 384;
    W2t[q] = f2bn(W2w[(size_t)h*36864 + (size_t)k*96 + n]);
  }
}

// ---------------------------------------------------------------------------
// Kernel 2 (v4, pipelined): Hi = emb @ B1 + P_b.
// BM=256, BN=128, BK=64, 4 waves (2x2), wave tile 128x64, acc[8][4].
// Single 48KB LDS buffer; A and B reg-staged; 2-phase K-loop:
//   { issue global loads t+1 -> regs }  overlaps  { ds_read+MFMA tile t }
//   __syncthreads  (vmcnt drain lands after compute)
//   ds_write regs -> LDS (tile t+1)
//   __syncthreads
// XOR-chunk swizzle (16B chunks, phys = logical ^ (row&7)) on ds_write and
// ds_read; writes land 2 lanes/bank (free), reads verified 0-conflict in R6.
// ---------------------------------------------------------------------------
__global__ __launch_bounds__(256, 2) void k_gemm1(const float* __restrict__ emb,
    const u16* __restrict__ B1t, const float* __restrict__ Pb, u16* __restrict__ Hi)
{
  __shared__ u16 As[256*64];   // 32 KB bf16 A tile (swizzled chunks)
  __shared__ u16 Bs[128*64];   // 16 KB bf16 B tile (swizzled chunks)
  const int tid  = threadIdx.x;
  const int lane = tid & 63;
  const int w    = tid >> 6;
  const int wr = w >> 1, wc = w & 1;            // wave tile: rows wr*128, cols wc*64
  const int L = blockIdx.x;                     // 0..1535, XCD-chunked swizzle
  const int widx = (L & 7) * 192 + (L >> 3);
  const int bm = widx / 6, bn = widx % 6;
  const int l15 = lane & 15, lg = lane >> 4;

  // staging geometry: 8 rows x 8 chunks of 16B per wave-issue
  const int srow   = lane >> 3;     // 0..7  (== row & 7 for all staged rows)
  const int schunk = lane & 7;      // logical 16B chunk within the row
  const int wchunk = schunk ^ srow; // physical (swizzled) chunk for ds_write

  // prefetch registers: A as 8x bf16x8 (cvt at arrival), B as 4x raw 16B
  bf16x8 pa[8];
  bf16x8 pb[4];

  // tile loader: global -> regs (A cvt fp32->bf16 immediately)
  auto load_tile = [&](int kt) {
    const int k0 = kt * 64;
    #pragma unroll
    for (int i = 0; i < 8; ++i) {
      const int row = w*64 + i*8 + srow;
      const float* src = emb + (size_t)(bm*256 + row)*Tsz + k0 + schunk*8;
      float4 v0 = *reinterpret_cast<const float4*>(src);
      float4 v1 = *reinterpret_cast<const float4*>(src + 4);
      bf16x8 af;
      af[0] = (__bf16)v0.x; af[1] = (__bf16)v0.y; af[2] = (__bf16)v0.z; af[3] = (__bf16)v0.w;
      af[4] = (__bf16)v1.x; af[5] = (__bf16)v1.y; af[6] = (__bf16)v1.z; af[7] = (__bf16)v1.w;
      pa[i] = af;
    }
    #pragma unroll
    for (int i = 0; i < 4; ++i) {
      const int row = w*32 + i*8 + srow;
      pb[i] = *reinterpret_cast<const bf16x8*>(
          B1t + (size_t)(bn*128 + row)*Tsz + k0 + schunk*8);
    }
  };
  // regs -> LDS (swizzled chunk)
  auto write_tile = [&]() {
    #pragma unroll
    for (int i = 0; i < 8; ++i) {
      const int row = w*64 + i*8 + srow;
      *reinterpret_cast<bf16x8*>(&As[row*64 + wchunk*8]) = pa[i];
    }
    #pragma unroll
    for (int i = 0; i < 4; ++i) {
      const int row = w*32 + i*8 + srow;
      *reinterpret_cast<bf16x8*>(&Bs[row*64 + wchunk*8]) = pb[i];
    }
  };

  f32x4 acc[8][4] = {};

  // prologue: tile 0
  load_tile(0);
  write_tile();
  __syncthreads();

  #pragma unroll 1
  for (int kt = 0; kt < 12; ++kt) {
    if (kt < 11) load_tile(kt + 1);   // in flight under compute
    // compute tile kt from LDS
    #pragma unroll
    for (int kk = 0; kk < 2; ++kk) {
      const int clog = kk*4 + lg;
      bf16x8 b[4];
      #pragma unroll
      for (int c = 0; c < 4; ++c) {
        const int Rb = wc*64 + c*16 + l15;
        b[c] = *reinterpret_cast<const bf16x8*>(&Bs[Rb*64 + (clog ^ (Rb & 7))*8]);
      }
      bf16x8 a[8];
      #pragma unroll
      for (int m = 0; m < 8; ++m) {
        const int R = wr*128 + m*16 + l15;
        a[m] = *reinterpret_cast<const bf16x8*>(&As[R*64 + (clog ^ (R & 7))*8]);
      }
      #pragma unroll
      for (int m = 0; m < 8; ++m)
        #pragma unroll
        for (int c = 0; c < 4; ++c)
          acc[m][c] = __builtin_amdgcn_mfma_f32_16x16x32_bf16(a[m], b[c], acc[m][c], 0, 0, 0);
    }
    __syncthreads();                  // reads of kt done everywhere
    if (kt < 11) {
      write_tile();                   // publish tile kt+1
      __syncthreads();
    }
  }

  // epilogue: bias + bf16 store (C layout: col=lane&15, row=(lane>>4)*4+j)
  #pragma unroll
  for (int c = 0; c < 4; ++c) {
    int col = bn*128 + wc*64 + c*16 + l15;
    float bias = Pb[col];
    #pragma unroll
    for (int m = 0; m < 8; ++m) {
      int row0 = bm*256 + wr*128 + m*16 + lg*4;
      #pragma unroll
      for (int j = 0; j < 4; ++j)
        Hi[(size_t)(row0 + j)*Ncols + col] = f2bn(acc[m][c][j] + bias);
    }
  }
}

// ---------------------------------------------------------------------------
// Kernel 3 (v4, unchanged): persistent per-(h,b) block, fused FFN + pool.
// ---------------------------------------------------------------------------
__global__ __launch_bounds__(256, 1) void k_ffn_pool(
    const u16* __restrict__ Hi, const u16* __restrict__ W1t, const u16* __restrict__ W2t,
    const float* __restrict__ b1, const float* __restrict__ b2v, const float* __restrict__ mask,
    float* __restrict__ out)
{
  __shared__ u16 W2s[96][392];              // 74.5 KB
  __shared__ u16 Zb[4][2][16][40];          // 10 KB
  __shared__ float mb[4][96], lb[4][96], ab[4][96];  // 4.5 KB

  const int tid = threadIdx.x, lane = tid & 63, w = tid >> 6;
  const int l15 = lane & 15, lg = lane >> 4;
  const int h = blockIdx.x, b = blockIdx.y;

  const u16* W1h = W1t + (size_t)h * DHID * DH;
  const u16* W2h = W2t + (size_t)h * DH * DHID;
  const float* b1h = b1 + h * DHID;

  for (int i = tid; i < 96*48; i += 256) {
    int r = i / 48, g = i % 48;
    uint4 v = *reinterpret_cast<const uint4*>(W2h + (size_t)r*DHID + g*8);
    *reinterpret_cast<uint4*>(&W2s[r][g*8]) = v;
  }
  __syncthreads();

  float b2s[6];
  #pragma unroll
  for (int ct = 0; ct < 6; ++ct) b2s[ct] = b2v[h*DH + ct*16 + l15];

  float Mr[6], Lr[6], Ar[6];
  #pragma unroll
  for (int ct = 0; ct < 6; ++ct) { Mr[ct] = -3.4e38f; Lr[ct] = 0.f; Ar[ct] = 0.f; }

  #pragma unroll 1
  for (int pass = 0; pass < 8; ++pass) {
    const size_t prow = (size_t)b*Ssz + (size_t)w*512 + (size_t)pass*64;

    bf16x8 hifr[4][3];
    #pragma unroll
    for (int s = 0; s < 4; ++s)
      #pragma unroll
      for (int ks = 0; ks < 3; ++ks)
        hifr[s][ks] = *reinterpret_cast<const bf16x8*>(
            Hi + (prow + s*16 + l15)*Ncols + h*DH + ks*32 + lg*8);

    f32x4 lgt[4][6] = {};

    #pragma unroll 2
    for (int c = 0; c < 12; ++c) {
      bf16x8 a1c[2][3];
      #pragma unroll
      for (int t = 0; t < 2; ++t)
        #pragma unroll
        for (int ks = 0; ks < 3; ++ks)
          a1c[t][ks] = *reinterpret_cast<const bf16x8*>(
              W1h + (size_t)(c*32 + t*16 + l15)*DH + ks*32 + lg*8);
      float4 bc0 = *reinterpret_cast<const float4*>(b1h + c*32 + lg*4);
      float4 bc1 = *reinterpret_cast<const float4*>(b1h + c*32 + 16 + lg*4);
      bf16x8 b2fr[6];
      #pragma unroll
      for (int ct = 0; ct < 6; ++ct)
        b2fr[ct] = *reinterpret_cast<const bf16x8*>(&W2s[ct*16 + l15][c*32 + lg*8]);

      #pragma unroll
      for (int bi = 0; bi < 2; ++bi) {
        f32x4 z[2][2];
        #pragma unroll
        for (int sl = 0; sl < 2; ++sl) {
          z[sl][0] = f32x4{}; z[sl][1] = f32x4{};
          #pragma unroll
          for (int ks = 0; ks < 3; ++ks) {
            z[sl][0] = __builtin_amdgcn_mfma_f32_16x16x32_bf16(a1c[0][ks], hifr[bi*2+sl][ks], z[sl][0], 0, 0, 0);
            z[sl][1] = __builtin_amdgcn_mfma_f32_16x16x32_bf16(a1c[1][ks], hifr[bi*2+sl][ks], z[sl][1], 0, 0, 0);
          }
        }
        #pragma unroll
        for (int sl = 0; sl < 2; ++sl) {
          bf16x4 p0, p1;
          p0[0] = (__bf16)fmaxf(z[sl][0][0] + bc0.x, 0.f);
          p0[1] = (__bf16)fmaxf(z[sl][0][1] + bc0.y, 0.f);
          p0[2] = (__bf16)fmaxf(z[sl][0][2] + bc0.z, 0.f);
          p0[3] = (__bf16)fmaxf(z[sl][0][3] + bc0.w, 0.f);
          p1[0] = (__bf16)fmaxf(z[sl][1][0] + bc1.x, 0.f);
          p1[1] = (__bf16)fmaxf(z[sl][1][1] + bc1.y, 0.f);
          p1[2] = (__bf16)fmaxf(z[sl][1][2] + bc1.z, 0.f);
          p1[3] = (__bf16)fmaxf(z[sl][1][3] + bc1.w, 0.f);
          *reinterpret_cast<uint2*>(&Zb[w][sl][l15][lg*4])      = __builtin_bit_cast(uint2, p0);
          *reinterpret_cast<uint2*>(&Zb[w][sl][l15][16 + lg*4]) = __builtin_bit_cast(uint2, p1);
        }
        #pragma unroll
        for (int sl = 0; sl < 2; ++sl) {
          bf16x8 zf = *reinterpret_cast<const bf16x8*>(&Zb[w][sl][l15][lg*8]);
          #pragma unroll
          for (int ct = 0; ct < 6; ++ct)
            lgt[bi*2+sl][ct] = __builtin_amdgcn_mfma_f32_16x16x32_bf16(zf, b2fr[ct], lgt[bi*2+sl][ct], 0, 0, 0);
        }
      }
    }

    float lmv[4][4];
    #pragma unroll
    for (int s = 0; s < 4; ++s) {
      float4 mk = *reinterpret_cast<const float4*>(&mask[prow + s*16 + lg*4]);
      lmv[s][0] = __logf(mk.x); lmv[s][1] = __logf(mk.y);
      lmv[s][2] = __logf(mk.z); lmv[s][3] = __logf(mk.w);
    }
    float G[4][6][4];
    #pragma unroll
    for (int s = 0; s < 4; ++s)
      #pragma unroll
      for (int ct = 0; ct < 6; ++ct)
        #pragma unroll
        for (int j = 0; j < 4; ++j)
          G[s][ct][j] = b2f(Hi[(prow + s*16 + lg*4 + j)*Ncols + h*DH + ct*16 + l15]);

    #pragma unroll
    for (int ct = 0; ct < 6; ++ct) {
      float av[4][4];
      float m16 = -3.4e38f;
      #pragma unroll
      for (int s = 0; s < 4; ++s)
        #pragma unroll
        for (int j = 0; j < 4; ++j) {
          av[s][j] = lgt[s][ct][j] + b2s[ct] + lmv[s][j];
          m16 = fmaxf(m16, av[s][j]);
        }
      m16 = fmaxf(m16, __shfl_xor(m16, 16));
      m16 = fmaxf(m16, __shfl_xor(m16, 32));
      float l16 = 0.f, a16 = 0.f;
      #pragma unroll
      for (int s = 0; s < 4; ++s)
        #pragma unroll
        for (int j = 0; j < 4; ++j) {
          float p = __expf(av[s][j] - m16);
          l16 += p;
          a16 += p * G[s][ct][j];
        }
      l16 += __shfl_xor(l16, 16); l16 += __shfl_xor(l16, 32);
      a16 += __shfl_xor(a16, 16); a16 += __shfl_xor(a16, 32);
      float M2 = fmaxf(Mr[ct], m16);
      float eo = __expf(Mr[ct] - M2), en = __expf(m16 - M2);
      Lr[ct] = Lr[ct]*eo + l16*en;
      Ar[ct] = Ar[ct]*eo + a16*en;
      Mr[ct] = M2;
    }
  }

  if (lane < 16) {
    #pragma unroll
    for (int ct = 0; ct < 6; ++ct) {
      mb[w][ct*16 + l15] = Mr[ct];
      lb[w][ct*16 + l15] = Lr[ct];
      ab[w][ct*16 + l15] = Ar[ct];
    }
  }
  __syncthreads();
  if (tid < 96) {
    float m = fmaxf(fmaxf(mb[0][tid], mb[1][tid]), fmaxf(mb[2][tid], mb[3][tid]));
    float l = 0.f, a = 0.f;
    #pragma unroll
    for (int q = 0; q < 4; ++q) {
      float sc = __expf(mb[q][tid] - m);
      l += lb[q][tid] * sc;
      a += ab[q][tid] * sc;
    }
    out[(size_t)b * Ncols + h*DH + tid] = a / l;
  }
}

// ---------------------------------------------------------------------------
// Workspace layout (bytes), total ~103 MB:
//   Hi  bf16 : 0           (100663296)
//   B1t bf16 : 100663296   (1179648)
//   W1t bf16 : 101842944   (589824)
//   W2t bf16 : 102432768   (589824)
// ---------------------------------------------------------------------------
extern "C" void kernel_launch(void* const* d_in, const int* in_sizes, int n_in,
                              void* d_out, int out_size, void* d_ws, size_t ws_size,
                              hipStream_t stream)
{
  const float* emb  = (const float*)d_in[0];
  const float* mask = (const float*)d_in[1];
  const float* Pw   = (const float*)d_in[2];
  const float* Pb   = (const float*)d_in[3];
  const float* W1w  = (const float*)d_in[4];
  const float* W1b  = (const float*)d_in[5];
  const float* W2w  = (const float*)d_in[6];
  const float* W2b  = (const float*)d_in[7];
  float* out = (float*)d_out;

  char* ws = (char*)d_ws;
  u16*   Hi  = (u16*)(ws);
  u16*   B1t = (u16*)(ws + 100663296ull);
  u16*   W1t = (u16*)(ws + 101842944ull);
  u16*   W2t = (u16*)(ws + 102432768ull);

  k_pack<<<dim3(4608), dim3(256), 0, stream>>>(Pw, W1w, W2w, B1t, W1t, W2t);
  k_gemm1<<<dim3(1536), dim3(256), 0, stream>>>(emb, B1t, Pb, Hi);
  k_ffn_pool<<<dim3(8, 32), dim3(256), 0, stream>>>(Hi, W1t, W2t, W1b, W2b, mask, out);
}

// Round 8
// 253.529 us; speedup vs baseline: 1.5992x; 1.0827x over previous
//
#include <hip/hip_runtime.h>
#include <cstdint>
#include <cstddef>

// Problem constants
#define Bsz   32
#define Ssz   2048
#define Tsz   768
#define NH    8
#define DH    96
#define DHID  384
#define Ncols (NH*DH)       // 768

using u16 = unsigned short;
typedef __bf16 bf16x8 __attribute__((ext_vector_type(8)));
typedef __bf16 bf16x4 __attribute__((ext_vector_type(4)));
typedef float  f32x4  __attribute__((ext_vector_type(4)));

__device__ __forceinline__ u16 f2bn(float f) {
  __bf16 h = (__bf16)f;
  return __builtin_bit_cast(u16, h);
}
__device__ __forceinline__ float b2f(u16 u) {
  return __builtin_bit_cast(float, (uint32_t)u << 16);
}

// ---------------------------------------------------------------------------
// Kernel 1: pack weights to bf16 (transposed, K-contiguous)  [unchanged]
// ---------------------------------------------------------------------------
__global__ __launch_bounds__(256) void k_pack(const float* __restrict__ Pw,
    const float* __restrict__ W1w, const float* __restrict__ W2w,
    u16* __restrict__ B1t, u16* __restrict__ W1t, u16* __restrict__ W2t)
{
  int i = blockIdx.x * 256 + threadIdx.x;
  if (i < 589824) {
    int n = i / 768, k = i % 768;
    int h = n / 96, d = n % 96;
    B1t[i] = f2bn(Pw[(size_t)h*73728 + (size_t)k*96 + d]);
  } else if (i < 589824 + 294912) {
    int j = i - 589824;
    int h = j / 36864, r = j % 36864;
    int n = r / 96, k = r % 96;
    W1t[j] = f2bn(W1w[(size_t)h*36864 + (size_t)k*384 + n]);
  } else if (i < 589824 + 2*294912) {
    int q = i - 589824 - 294912;
    int h = q / 36864, r = q % 36864;
    int n = r / 384, k = r % 384;
    W2t[q] = f2bn(W2w[(size_t)h*36864 + (size_t)k*96 + n]);
  }
}

// ---------------------------------------------------------------------------
// Kernel 2 (v5): Hi = emb @ B1 + P_b.
// BM=256, BN=256, BK=64, 8 waves (2x4), wave tile 128x64, acc[8][4].
// Rationale: A-panel redundancy 6x -> 3x; the pipeline is VMEM-byte-bound
// (~9 TB/s aggregate observed across R4-R7), so bytes/CU is the lever.
// Reg-staged A (fp32->bf16 cvt at arrival) + B; single LDS buffer; 2-phase
// K-loop (loads for t+1 in flight under compute of t). XOR-chunk swizzle
// phys = logical ^ (row&7) on ds_write and ds_read (0-conflict, verified R6/7).
// ---------------------------------------------------------------------------
__global__ __launch_bounds__(512, 1) void k_gemm1(const float* __restrict__ emb,
    const u16* __restrict__ B1t, const float* __restrict__ Pb, u16* __restrict__ Hi)
{
  __shared__ u16 As[256*64];   // 32 KB bf16 A tile (swizzled chunks)
  __shared__ u16 Bs[256*64];   // 32 KB bf16 B tile (swizzled chunks)
  const int tid  = threadIdx.x;
  const int lane = tid & 63;
  const int w    = tid >> 6;                    // 0..7
  const int wr = w >> 2, wc = w & 3;            // wave tile: rows wr*128, cols wc*64
  const int L = blockIdx.x;                     // 0..767, XCD-chunked swizzle
  const int widx = (L & 7) * 96 + (L >> 3);
  const int bm = widx / 3, bn = widx % 3;
  const int l15 = lane & 15, lg = lane >> 4;

  // staging geometry: 8 rows x 8 chunks of 16B(bf16)/32B(fp32) per wave-issue
  const int srow   = lane >> 3;     // 0..7 (== row & 7 for staged rows)
  const int schunk = lane & 7;      // logical 16B chunk within the row
  const int wchunk = schunk ^ srow; // physical (swizzled) chunk for ds_write

  bf16x8 pa[4];   // A prefetch (converted at arrival)
  bf16x8 pb[4];   // B prefetch (raw 16B)

  auto load_tile = [&](int kt) {
    const int k0 = kt * 64;
    #pragma unroll
    for (int i = 0; i < 4; ++i) {
      const int row = w*32 + i*8 + srow;
      const float* src = emb + (size_t)(bm*256 + row)*Tsz + k0 + schunk*8;
      float4 v0 = *reinterpret_cast<const float4*>(src);
      float4 v1 = *reinterpret_cast<const float4*>(src + 4);
      bf16x8 af;
      af[0] = (__bf16)v0.x; af[1] = (__bf16)v0.y; af[2] = (__bf16)v0.z; af[3] = (__bf16)v0.w;
      af[4] = (__bf16)v1.x; af[5] = (__bf16)v1.y; af[6] = (__bf16)v1.z; af[7] = (__bf16)v1.w;
      pa[i] = af;
    }
    #pragma unroll
    for (int i = 0; i < 4; ++i) {
      const int row = w*32 + i*8 + srow;
      pb[i] = *reinterpret_cast<const bf16x8*>(
          B1t + (size_t)(bn*256 + row)*Tsz + k0 + schunk*8);
    }
  };
  auto write_tile = [&]() {
    #pragma unroll
    for (int i = 0; i < 4; ++i) {
      const int row = w*32 + i*8 + srow;
      *reinterpret_cast<bf16x8*>(&As[row*64 + wchunk*8]) = pa[i];
      *reinterpret_cast<bf16x8*>(&Bs[row*64 + wchunk*8]) = pb[i];
    }
  };

  f32x4 acc[8][4] = {};

  load_tile(0);
  write_tile();
  __syncthreads();

  #pragma unroll 1
  for (int kt = 0; kt < 12; ++kt) {
    if (kt < 11) load_tile(kt + 1);   // in flight under compute
    #pragma unroll
    for (int kk = 0; kk < 2; ++kk) {
      const int clog = kk*4 + lg;
      bf16x8 b[4];
      #pragma unroll
      for (int c = 0; c < 4; ++c) {
        const int Rb = wc*64 + c*16 + l15;
        b[c] = *reinterpret_cast<const bf16x8*>(&Bs[Rb*64 + (clog ^ (Rb & 7))*8]);
      }
      bf16x8 a[8];
      #pragma unroll
      for (int m = 0; m < 8; ++m) {
        const int R = wr*128 + m*16 + l15;
        a[m] = *reinterpret_cast<const bf16x8*>(&As[R*64 + (clog ^ (R & 7))*8]);
      }
      #pragma unroll
      for (int m = 0; m < 8; ++m)
        #pragma unroll
        for (int c = 0; c < 4; ++c)
          acc[m][c] = __builtin_amdgcn_mfma_f32_16x16x32_bf16(a[m], b[c], acc[m][c], 0, 0, 0);
    }
    __syncthreads();
    if (kt < 11) {
      write_tile();
      __syncthreads();
    }
  }

  // epilogue: bias + bf16 store (C layout: col=lane&15, row=(lane>>4)*4+j)
  #pragma unroll
  for (int c = 0; c < 4; ++c) {
    int col = bn*256 + wc*64 + c*16 + l15;
    float bias = Pb[col];
    #pragma unroll
    for (int m = 0; m < 8; ++m) {
      int row0 = bm*256 + wr*128 + m*16 + lg*4;
      #pragma unroll
      for (int j = 0; j < 4; ++j)
        Hi[(size_t)(row0 + j)*Ncols + col] = f2bn(acc[m][c][j] + bias);
    }
  }
}

// ---------------------------------------------------------------------------
// Kernel 3 (v5): persistent per-(h,b) block, fused FFN + pool.
// NEW: W1_h ALSO staged in LDS (kills the 604 MB per-wave W1 re-stream that
// dominated at the ~9 TB/s VMEM ceiling). LDS: W1s 78KB + W2s 73.5KB +
// Zb(1 slot/wave) 5KB = 156.5KB. Merge buffers alias each wave's OWN Zb slot.
// ---------------------------------------------------------------------------
__global__ __launch_bounds__(256, 1) void k_ffn_pool(
    const u16* __restrict__ Hi, const u16* __restrict__ W1t, const u16* __restrict__ W2t,
    const float* __restrict__ b1, const float* __restrict__ b2v, const float* __restrict__ mask,
    float* __restrict__ out)
{
  __shared__ u16 W1s[384][104];    // 79872 B; stride 208B -> 2-way banks on b128 col reads
  __shared__ u16 W2s[96][392];     // 75264 B; stride 784B (verified pattern)
  __shared__ u16 Zb[4][16][40];    // 5120 B; one bounce slot per wave
  // per-wave merge buffers alias the wave's own Zb slot (1280B >= 3*96*4=1152B)

  const int tid = threadIdx.x, lane = tid & 63, w = tid >> 6;
  const int l15 = lane & 15, lg = lane >> 4;
  const int h = blockIdx.x, b = blockIdx.y;

  const u16* W1h = W1t + (size_t)h * DHID * DH;
  const u16* W2h = W2t + (size_t)h * DH * DHID;
  const float* b1h = b1 + h * DHID;

  // stage W1_h (384x96) and W2_h (96x384) -> LDS
  for (int i = tid; i < 384*12; i += 256) {
    int r = i / 12, g = i % 12;
    uint4 v = *reinterpret_cast<const uint4*>(W1h + (size_t)r*DH + g*8);
    *reinterpret_cast<uint4*>(&W1s[r][g*8]) = v;
  }
  for (int i = tid; i < 96*48; i += 256) {
    int r = i / 48, g = i % 48;
    uint4 v = *reinterpret_cast<const uint4*>(W2h + (size_t)r*DHID + g*8);
    *reinterpret_cast<uint4*>(&W2s[r][g*8]) = v;
  }
  __syncthreads();

  float b2s[6];
  #pragma unroll
  for (int ct = 0; ct < 6; ++ct) b2s[ct] = b2v[h*DH + ct*16 + l15];

  float Mr[6], Lr[6], Ar[6];
  #pragma unroll
  for (int ct = 0; ct < 6; ++ct) { Mr[ct] = -3.4e38f; Lr[ct] = 0.f; Ar[ct] = 0.f; }

  #pragma unroll 1
  for (int pass = 0; pass < 8; ++pass) {
    const size_t prow = (size_t)b*Ssz + (size_t)w*512 + (size_t)pass*64;

    bf16x8 hifr[4][3];
    #pragma unroll
    for (int s = 0; s < 4; ++s)
      #pragma unroll
      for (int ks = 0; ks < 3; ++ks)
        hifr[s][ks] = *reinterpret_cast<const bf16x8*>(
            Hi + (prow + s*16 + l15)*Ncols + h*DH + ks*32 + lg*8);

    f32x4 lgt[4][6] = {};

    #pragma unroll 2
    for (int c = 0; c < 12; ++c) {
      // W1 A-frags from LDS
      bf16x8 a1c[2][3];
      #pragma unroll
      for (int t = 0; t < 2; ++t)
        #pragma unroll
        for (int ks = 0; ks < 3; ++ks)
          a1c[t][ks] = *reinterpret_cast<const bf16x8*>(
              &W1s[c*32 + t*16 + l15][ks*32 + lg*8]);
      float4 bc0 = *reinterpret_cast<const float4*>(b1h + c*32 + lg*4);
      float4 bc1 = *reinterpret_cast<const float4*>(b1h + c*32 + 16 + lg*4);
      bf16x8 b2fr[6];
      #pragma unroll
      for (int ct = 0; ct < 6; ++ct)
        b2fr[ct] = *reinterpret_cast<const bf16x8*>(&W2s[ct*16 + l15][c*32 + lg*8]);

      #pragma unroll
      for (int s = 0; s < 4; ++s) {
        f32x4 z0 = {}, z1 = {};
        #pragma unroll
        for (int ks = 0; ks < 3; ++ks) {
          z0 = __builtin_amdgcn_mfma_f32_16x16x32_bf16(a1c[0][ks], hifr[s][ks], z0, 0, 0, 0);
          z1 = __builtin_amdgcn_mfma_f32_16x16x32_bf16(a1c[1][ks], hifr[s][ks], z1, 0, 0, 0);
        }
        bf16x4 p0, p1;
        p0[0] = (__bf16)fmaxf(z0[0] + bc0.x, 0.f);
        p0[1] = (__bf16)fmaxf(z0[1] + bc0.y, 0.f);
        p0[2] = (__bf16)fmaxf(z0[2] + bc0.z, 0.f);
        p0[3] = (__bf16)fmaxf(z0[3] + bc0.w, 0.f);
        p1[0] = (__bf16)fmaxf(z1[0] + bc1.x, 0.f);
        p1[1] = (__bf16)fmaxf(z1[1] + bc1.y, 0.f);
        p1[2] = (__bf16)fmaxf(z1[2] + bc1.z, 0.f);
        p1[3] = (__bf16)fmaxf(z1[3] + bc1.w, 0.f);
        *reinterpret_cast<uint2*>(&Zb[w][l15][lg*4])      = __builtin_bit_cast(uint2, p0);
        *reinterpret_cast<uint2*>(&Zb[w][l15][16 + lg*4]) = __builtin_bit_cast(uint2, p1);
        bf16x8 zf = *reinterpret_cast<const bf16x8*>(&Zb[w][l15][lg*8]);
        #pragma unroll
        for (int ct = 0; ct < 6; ++ct)
          lgt[s][ct] = __builtin_amdgcn_mfma_f32_16x16x32_bf16(zf, b2fr[ct], lgt[s][ct], 0, 0, 0);
      }
    }

    float lmv[4][4];
    #pragma unroll
    for (int s = 0; s < 4; ++s) {
      float4 mk = *reinterpret_cast<const float4*>(&mask[prow + s*16 + lg*4]);
      lmv[s][0] = __logf(mk.x); lmv[s][1] = __logf(mk.y);
      lmv[s][2] = __logf(mk.z); lmv[s][3] = __logf(mk.w);
    }
    float G[4][6][4];
    #pragma unroll
    for (int s = 0; s < 4; ++s)
      #pragma unroll
      for (int ct = 0; ct < 6; ++ct)
        #pragma unroll
        for (int j = 0; j < 4; ++j)
          G[s][ct][j] = b2f(Hi[(prow + s*16 + lg*4 + j)*Ncols + h*DH + ct*16 + l15]);

    #pragma unroll
    for (int ct = 0; ct < 6; ++ct) {
      float av[4][4];
      float m16 = -3.4e38f;
      #pragma unroll
      for (int s = 0; s < 4; ++s)
        #pragma unroll
        for (int j = 0; j < 4; ++j) {
          av[s][j] = lgt[s][ct][j] + b2s[ct] + lmv[s][j];
          m16 = fmaxf(m16, av[s][j]);
        }
      m16 = fmaxf(m16, __shfl_xor(m16, 16));
      m16 = fmaxf(m16, __shfl_xor(m16, 32));
      float l16 = 0.f, a16 = 0.f;
      #pragma unroll
      for (int s = 0; s < 4; ++s)
        #pragma unroll
        for (int j = 0; j < 4; ++j) {
          float p = __expf(av[s][j] - m16);
          l16 += p;
          a16 += p * G[s][ct][j];
        }
      l16 += __shfl_xor(l16, 16); l16 += __shfl_xor(l16, 32);
      a16 += __shfl_xor(a16, 16); a16 += __shfl_xor(a16, 32);
      float M2 = fmaxf(Mr[ct], m16);
      float eo = __expf(Mr[ct] - M2), en = __expf(m16 - M2);
      Lr[ct] = Lr[ct]*eo + l16*en;
      Ar[ct] = Ar[ct]*eo + a16*en;
      Mr[ct] = M2;
    }
  }

  // ---- block-level merge: each wave writes into ITS OWN Zb slot (alias) ----
  float* mw = reinterpret_cast<float*>(&Zb[w][0][0]);   // 1280B >= 1152B
  if (lane < 16) {
    #pragma unroll
    for (int ct = 0; ct < 6; ++ct) {
      mw[      ct*16 + l15] = Mr[ct];
      mw[ 96 + ct*16 + l15] = Lr[ct];
      mw[192 + ct*16 + l15] = Ar[ct];
    }
  }
  __syncthreads();
  if (tid < 96) {
    const float* m0 = reinterpret_cast<const float*>(&Zb[0][0][0]);
    const float* m1 = reinterpret_cast<const float*>(&Zb[1][0][0]);
    const float* m2 = reinterpret_cast<const float*>(&Zb[2][0][0]);
    const float* m3 = reinterpret_cast<const float*>(&Zb[3][0][0]);
    float m = fmaxf(fmaxf(m0[tid], m1[tid]), fmaxf(m2[tid], m3[tid]));
    float e0 = __expf(m0[tid] - m), e1 = __expf(m1[tid] - m);
    float e2 = __expf(m2[tid] - m), e3 = __expf(m3[tid] - m);
    float l = m0[96+tid]*e0 + m1[96+tid]*e1 + m2[96+tid]*e2 + m3[96+tid]*e3;
    float a = m0[192+tid]*e0 + m1[192+tid]*e1 + m2[192+tid]*e2 + m3[192+tid]*e3;
    out[(size_t)b * Ncols + h*DH + tid] = a / l;
  }
}

// ---------------------------------------------------------------------------
// Workspace layout (bytes), total ~103 MB:
//   Hi  bf16 : 0           (100663296)
//   B1t bf16 : 100663296   (1179648)
//   W1t bf16 : 101842944   (589824)
//   W2t bf16 : 102432768   (589824)
// ---------------------------------------------------------------------------
extern "C" void kernel_launch(void* const* d_in, const int* in_sizes, int n_in,
                              void* d_out, int out_size, void* d_ws, size_t ws_size,
                              hipStream_t stream)
{
  const float* emb  = (const float*)d_in[0];
  const float* mask = (const float*)d_in[1];
  const float* Pw   = (const float*)d_in[2];
  const float* Pb   = (const float*)d_in[3];
  const float* W1w  = (const float*)d_in[4];
  const float* W1b  = (const float*)d_in[5];
  const float* W2w  = (const float*)d_in[6];
  const float* W2b  = (const float*)d_in[7];
  float* out = (float*)d_out;

  char* ws = (char*)d_ws;
  u16*   Hi  = (u16*)(ws);
  u16*   B1t = (u16*)(ws + 100663296ull);
  u16*   W1t = (u16*)(ws + 101842944ull);
  u16*   W2t = (u16*)(ws + 102432768ull);

  k_pack<<<dim3(4608), dim3(256), 0, stream>>>(Pw, W1w, W2w, B1t, W1t, W2t);
  k_gemm1<<<dim3(768), dim3(512), 0, stream>>>(emb, B1t, Pb, Hi);
  k_ffn_pool<<<dim3(8, 32), dim3(256), 0, stream>>>(Hi, W1t, W2t, W1b, W2b, mask, out);
}